// Round 4
// baseline (1407.039 us; speedup 1.0000x reference)
//
#include <hip/hip_runtime.h>
#include <hip/hip_bf16.h>

// GCN inference: conv1(128->16)+ReLU -> conv2(16->16) -> linear(16->40) -> log_softmax
// Primary: build CSR-by-col once per call (count/scan/scatter with precomputed
// norm), then atomic-free aggregation with 16 lanes per node.
// Fallback (ws_size < 65.3 MB): atomic scatter-add aggregation, needs 13.2 MB.
// Branch on ws_size is constant per session -> same work every call (capture-safe).
// (Round 3: resubmission — rounds 0-2 all failed at container acquisition,
//  including the empty stub, so failures are infra, not kernel.)

#define N_NODES 100000
#define N_EDGES 6400000
#define IN_DIM  128
#define HID     16
#define NCLS    40

// ---- full-path workspace layout (bytes) ----
#define OFF_DEG   0          // float[N]  (becomes dinv in place)
#define OFF_CNT   400128     // int[N]    (becomes scatter cursor after scan)
#define OFF_OFFS  800256     // int[N+1]
#define OFF_EDATA 1200384    // int2[E]   (row, norm-as-int)
#define OFF_H1    52400384   // float[N*16]
#define OFF_HB    58800384   // float[N*16]
#define OFF_BSUM  65200384   // int[98]
#define WS_FULL_NEED 65210000

// ---- fallback workspace layout ----
#define OFF2_DEG 0           // float[N]
#define OFF2_H1  400128      // float[N*16] (aggregation target)
#define OFF2_HB  6800384     // float[N*16] (pre-agg features)

__global__ __launch_bounds__(256) void k_init(float* deg, int* cnt) {
    int i = blockIdx.x * 256 + threadIdx.x;
    if (i < N_NODES) { deg[i] = 1.0f; cnt[i] = 0; }   // self-loop weight 1
}

__global__ __launch_bounds__(256) void k_deg_count(const int* col, const float* w,
                                                   float* deg, int* cnt) {
    int e = blockIdx.x * 256 + threadIdx.x;           // grid covers E exactly
    int c = col[e];
    atomicAdd(&deg[c], w[e]);
    atomicAdd(&cnt[c], 1);
}

__global__ __launch_bounds__(256) void k_dinv(float* deg) {
    int i = blockIdx.x * 256 + threadIdx.x;
    if (i < N_NODES) {
        float d = deg[i];
        deg[i] = (d > 0.0f) ? 1.0f / sqrtf(d) : 0.0f;
    }
}

// ---- 3-kernel exclusive scan of cnt[N] -> offs[N+1] ----
__global__ __launch_bounds__(1024) void k_scan1(const int* cnt, int* offs, int* bsum) {
    __shared__ int s[1024];
    int tid = threadIdx.x;
    int gid = blockIdx.x * 1024 + tid;
    int v = (gid < N_NODES) ? cnt[gid] : 0;
    s[tid] = v;
    __syncthreads();
    for (int o = 1; o < 1024; o <<= 1) {
        int t = (tid >= o) ? s[tid - o] : 0;
        __syncthreads();
        s[tid] += t;
        __syncthreads();
    }
    if (gid < N_NODES) offs[gid] = s[tid] - v;        // block-local exclusive
    if (tid == 1023) bsum[blockIdx.x] = s[1023];
}

__global__ __launch_bounds__(128) void k_scan2(int* bsum) {
    __shared__ int s[128];
    int tid = threadIdx.x;
    int v = (tid < 98) ? bsum[tid] : 0;
    s[tid] = v;
    __syncthreads();
    for (int o = 1; o < 128; o <<= 1) {
        int t = (tid >= o) ? s[tid - o] : 0;
        __syncthreads();
        s[tid] += t;
        __syncthreads();
    }
    if (tid < 98) bsum[tid] = s[tid] - v;             // exclusive block offsets
}

__global__ __launch_bounds__(1024) void k_scan3(int* offs, int* cur, const int* bsum) {
    int tid = threadIdx.x;
    int gid = blockIdx.x * 1024 + tid;
    if (gid < N_NODES) {
        int o = offs[gid] + bsum[blockIdx.x];
        offs[gid] = o;
        cur[gid] = o;                                  // scatter cursor (reuses cnt buf)
    }
    if (gid == 0) offs[N_NODES] = N_EDGES;
}

__global__ __launch_bounds__(256) void k_scatter(const int* row, const int* col,
                                                 const float* w, const float* dinv,
                                                 int* cur, int2* edata) {
    int e = blockIdx.x * 256 + threadIdx.x;           // grid covers E exactly
    int r = row[e];
    int c = col[e];
    float nrm = dinv[r] * w[e] * dinv[c];
    int p = atomicAdd(&cur[c], 1);
    edata[p] = make_int2(r, __float_as_int(nrm));
}

// h1 = z @ W1   [100000,128] @ [128,16]
__global__ __launch_bounds__(256) void k_gemm1(const float* z, const float* W1, float* h1) {
    __shared__ float w1s[IN_DIM * HID];               // 8 KB
    __shared__ float zs[64 * 132];                    // 64 rows, pad 128->132 (bank-safe)
    int tid = threadIdx.x;
    for (int i = tid; i < IN_DIM * HID / 4; i += 256)
        ((float4*)w1s)[i] = ((const float4*)W1)[i];
    int nodeBase = blockIdx.x * 64;
    for (int i = tid; i < 64 * 32; i += 256) {        // 2048 float4 loads, coalesced
        int nl = i >> 5, kq = i & 31;
        int node = nodeBase + nl;
        float4 v = (node < N_NODES) ? ((const float4*)z)[node * 32 + kq]
                                    : make_float4(0.f, 0.f, 0.f, 0.f);
        *(float4*)&zs[nl * 132 + kq * 4] = v;         // 132*4=528 bytes, 16B-aligned
    }
    __syncthreads();
    int nl = tid >> 2;
    int jb = (tid & 3) * 4;
    int node = nodeBase + nl;
    float4 acc = make_float4(0.f, 0.f, 0.f, 0.f);
    for (int k = 0; k < IN_DIM; k++) {
        float s = zs[nl * 132 + k];
        float4 wv = *(const float4*)&w1s[k * HID + jb];
        acc.x += s * wv.x; acc.y += s * wv.y; acc.z += s * wv.z; acc.w += s * wv.w;
    }
    if (node < N_NODES) ((float4*)h1)[node * 4 + (tid & 3)] = acc;
}

// aggregate conv1 (+b1, ReLU) then fused h2 = x1 @ W2 via in-wave shuffles.
// 16 lanes per node; grid 6250 * 16 = 100000 exactly (no partial groups).
__global__ __launch_bounds__(256) void k_agg1(const float* h1, const float* dinv,
                                              const int* offs, const int2* edata,
                                              const float* b1, const float* W2, float* hb) {
    __shared__ float w2s[HID * HID];
    int tid = threadIdx.x;
    if (tid < HID * HID) w2s[tid] = W2[tid];
    __syncthreads();
    int lane = tid & 15;
    int node = blockIdx.x * 16 + (tid >> 4);
    float d = dinv[node];
    float acc = d * d * h1[node * HID + lane];        // self-loop term
    int e0 = offs[node], e1 = offs[node + 1];
    for (int e = e0; e < e1; e++) {
        int2 ed = edata[e];
        acc += __int_as_float(ed.y) * h1[ed.x * HID + lane];
    }
    acc += b1[lane];
    acc = fmaxf(acc, 0.0f);                           // ReLU
    int base = tid & 48;                              // 16-lane group base in wave
    float h2 = 0.0f;
    for (int k = 0; k < HID; k++) {
        float v = __shfl(acc, base + k, 64);
        h2 += v * w2s[k * HID + lane];
    }
    hb[node * HID + lane] = h2;
}

// aggregate conv2 (+b2), fused classifier (16->40) + log_softmax, writes d_out.
__global__ __launch_bounds__(256) void k_agg2(const float* hb, const float* dinv,
                                              const int* offs, const int2* edata,
                                              const float* b2, const float* Wc,
                                              const float* bc, float* out) {
    __shared__ float wcs[HID * NCLS];                 // 640 floats
    __shared__ float bcs[NCLS];
    int tid = threadIdx.x;
    for (int i = tid; i < HID * NCLS; i += 256) wcs[i] = Wc[i];
    if (tid < NCLS) bcs[tid] = bc[tid];
    __syncthreads();
    int lane = tid & 15;
    int node = blockIdx.x * 16 + (tid >> 4);
    float d = dinv[node];
    float acc = d * d * hb[node * HID + lane];
    int e0 = offs[node], e1 = offs[node + 1];
    for (int e = e0; e < e1; e++) {
        int2 ed = edata[e];
        acc += __int_as_float(ed.y) * hb[ed.x * HID + lane];
    }
    acc += b2[lane];
    // classifier: lane j owns logits j, j+16, and j+32 (j<8)
    float l0 = bcs[lane];
    float l1 = bcs[lane + 16];
    float l2 = (lane < 8) ? bcs[lane + 32] : 0.0f;
    int base = tid & 48;
    for (int k = 0; k < HID; k++) {
        float v = __shfl(acc, base + k, 64);
        l0 += v * wcs[k * NCLS + lane];
        l1 += v * wcs[k * NCLS + lane + 16];
        if (lane < 8) l2 += v * wcs[k * NCLS + lane + 32];
    }
    // log_softmax over the 40 values held by this 16-lane group
    float m = fmaxf(l0, l1);
    if (lane < 8) m = fmaxf(m, l2);
    for (int o = 1; o < 16; o <<= 1) m = fmaxf(m, __shfl_xor(m, o, 64));
    float s = expf(l0 - m) + expf(l1 - m) + ((lane < 8) ? expf(l2 - m) : 0.0f);
    for (int o = 1; o < 16; o <<= 1) s += __shfl_xor(s, o, 64);
    float ls = logf(s) + m;
    out[node * NCLS + lane] = l0 - ls;
    out[node * NCLS + lane + 16] = l1 - ls;
    if (lane < 8) out[node * NCLS + lane + 32] = l2 - ls;
}

// ==================== fallback path (small workspace) ====================

__global__ __launch_bounds__(256) void k_init_deg(float* deg) {
    int i = blockIdx.x * 256 + threadIdx.x;
    if (i < N_NODES) deg[i] = 1.0f;
}

__global__ __launch_bounds__(256) void k_deg_only(const int* col, const float* w, float* deg) {
    int e = blockIdx.x * 256 + threadIdx.x;
    atomicAdd(&deg[col[e]], w[e]);
}

// agg[i] = dinv[node]^2 * h[i]   (self-loop init), N*16 threads
__global__ __launch_bounds__(256) void k_self(const float* dinv, const float* h, float* agg) {
    int i = blockIdx.x * 256 + threadIdx.x;           // 6250 blocks exact
    float d = dinv[i >> 4];
    agg[i] = d * d * h[i];
}

// one thread per (edge,lane): agg[c*16+l] += norm * h[r*16+l], E*16 threads
__global__ __launch_bounds__(256) void k_edge_atomic(const int* row, const int* col,
                                                     const float* w, const float* dinv,
                                                     const float* h, float* agg) {
    int gid = blockIdx.x * 256 + threadIdx.x;         // 400000 blocks exact
    int e = gid >> 4, lane = gid & 15;
    int r = row[e], c = col[e];
    float nrm = dinv[r] * w[e] * dinv[c];
    atomicAdd(&agg[c * HID + lane], nrm * h[r * HID + lane]);
}

// x2 = relu(agg + b1) @ W2, per-node 16 lanes (shuffle matmul)
__global__ __launch_bounds__(256) void k_bias_relu_gemm2(const float* agg, const float* b1,
                                                         const float* W2, float* out2) {
    __shared__ float w2s[HID * HID];
    int tid = threadIdx.x;
    if (tid < HID * HID) w2s[tid] = W2[tid];
    __syncthreads();
    int lane = tid & 15;
    int node = blockIdx.x * 16 + (tid >> 4);
    float acc = fmaxf(agg[node * HID + lane] + b1[lane], 0.0f);
    int base = tid & 48;
    float h2 = 0.0f;
    for (int k = 0; k < HID; k++) {
        float v = __shfl(acc, base + k, 64);
        h2 += v * w2s[k * HID + lane];
    }
    out2[node * HID + lane] = h2;
}

// out = log_softmax((agg + b2) @ Wc + bc)
__global__ __launch_bounds__(256) void k_final(const float* agg, const float* b2,
                                               const float* Wc, const float* bc, float* out) {
    __shared__ float wcs[HID * NCLS];
    __shared__ float bcs[NCLS];
    int tid = threadIdx.x;
    for (int i = tid; i < HID * NCLS; i += 256) wcs[i] = Wc[i];
    if (tid < NCLS) bcs[tid] = bc[tid];
    __syncthreads();
    int lane = tid & 15;
    int node = blockIdx.x * 16 + (tid >> 4);
    float acc = agg[node * HID + lane] + b2[lane];
    float l0 = bcs[lane];
    float l1 = bcs[lane + 16];
    float l2 = (lane < 8) ? bcs[lane + 32] : 0.0f;
    int base = tid & 48;
    for (int k = 0; k < HID; k++) {
        float v = __shfl(acc, base + k, 64);
        l0 += v * wcs[k * NCLS + lane];
        l1 += v * wcs[k * NCLS + lane + 16];
        if (lane < 8) l2 += v * wcs[k * NCLS + lane + 32];
    }
    float m = fmaxf(l0, l1);
    if (lane < 8) m = fmaxf(m, l2);
    for (int o = 1; o < 16; o <<= 1) m = fmaxf(m, __shfl_xor(m, o, 64));
    float s = expf(l0 - m) + expf(l1 - m) + ((lane < 8) ? expf(l2 - m) : 0.0f);
    for (int o = 1; o < 16; o <<= 1) s += __shfl_xor(s, o, 64);
    float ls = logf(s) + m;
    out[node * NCLS + lane] = l0 - ls;
    out[node * NCLS + lane + 16] = l1 - ls;
    if (lane < 8) out[node * NCLS + lane + 32] = l2 - ls;
}

extern "C" void kernel_launch(void* const* d_in, const int* in_sizes, int n_in,
                              void* d_out, int out_size, void* d_ws, size_t ws_size,
                              hipStream_t stream) {
    const float* z     = (const float*)d_in[0];
    const int*   eidx  = (const int*)d_in[1];       // [2, E] int32
    const float* eattr = (const float*)d_in[2];
    const float* W1    = (const float*)d_in[3];
    const float* b1    = (const float*)d_in[4];
    const float* W2    = (const float*)d_in[5];
    const float* b2    = (const float*)d_in[6];
    const float* Wc    = (const float*)d_in[7];
    const float* bc    = (const float*)d_in[8];
    float* out = (float*)d_out;

    char* ws = (char*)d_ws;
    const int* rowp = eidx;
    const int* colp = eidx + N_EDGES;

    int nblk  = (N_NODES + 255) / 256;              // 391
    int eblk  = N_EDGES / 256;                      // 25000 exact
    int sblk  = (N_NODES + 1023) / 1024;            // 98
    int gblk  = (N_NODES + 63) / 64;                // 1563
    int ablk  = N_NODES / 16;                       // 6250
    int fblk  = (N_NODES * HID) / 256;              // 6250
    int exblk = (N_EDGES * HID) / 256;              // 400000

    if (ws_size >= (size_t)WS_FULL_NEED) {
        // ---------- CSR path ----------
        float* deg  = (float*)(ws + OFF_DEG);       // becomes dinv
        int*   cnt  = (int*)(ws + OFF_CNT);         // becomes cursor
        int*   offs = (int*)(ws + OFF_OFFS);
        int2*  edat = (int2*)(ws + OFF_EDATA);
        float* h1   = (float*)(ws + OFF_H1);
        float* hb   = (float*)(ws + OFF_HB);
        int*   bsum = (int*)(ws + OFF_BSUM);

        k_init<<<nblk, 256, 0, stream>>>(deg, cnt);
        k_deg_count<<<eblk, 256, 0, stream>>>(colp, eattr, deg, cnt);
        k_dinv<<<nblk, 256, 0, stream>>>(deg);
        k_scan1<<<sblk, 1024, 0, stream>>>(cnt, offs, bsum);
        k_scan2<<<1, 128, 0, stream>>>(bsum);
        k_scan3<<<sblk, 1024, 0, stream>>>(offs, cnt, bsum);
        k_scatter<<<eblk, 256, 0, stream>>>(rowp, colp, eattr, deg, cnt, edat);
        k_gemm1<<<gblk, 256, 0, stream>>>(z, W1, h1);
        k_agg1<<<ablk, 256, 0, stream>>>(h1, deg, offs, edat, b1, W2, hb);
        k_agg2<<<ablk, 256, 0, stream>>>(hb, deg, offs, edat, b2, Wc, bc, out);
    } else {
        // ---------- atomic fallback (13.2 MB) ----------
        float* deg = (float*)(ws + OFF2_DEG);
        float* h1  = (float*)(ws + OFF2_H1);        // aggregation target
        float* hb  = (float*)(ws + OFF2_HB);        // pre-agg features

        k_init_deg<<<nblk, 256, 0, stream>>>(deg);
        k_deg_only<<<eblk, 256, 0, stream>>>(colp, eattr, deg);
        k_dinv<<<nblk, 256, 0, stream>>>(deg);
        k_gemm1<<<gblk, 256, 0, stream>>>(z, W1, hb);
        k_self<<<fblk, 256, 0, stream>>>(deg, hb, h1);
        k_edge_atomic<<<exblk, 256, 0, stream>>>(rowp, colp, eattr, deg, hb, h1);
        k_bias_relu_gemm2<<<ablk, 256, 0, stream>>>(h1, b1, W2, hb);
        k_self<<<fblk, 256, 0, stream>>>(deg, hb, h1);
        k_edge_atomic<<<exblk, 256, 0, stream>>>(rowp, colp, eattr, deg, hb, h1);
        k_final<<<ablk, 256, 0, stream>>>(h1, b2, Wc, bc, out);
    }
}

// Round 5
// 1163.614 us; speedup vs baseline: 1.2092x; 1.2092x over previous
//
#include <hip/hip_runtime.h>
#include <hip/hip_bf16.h>

// GCN inference: conv1(128->16)+ReLU -> conv2(16->16) -> linear(16->40) -> log_softmax
// R4: k_deg_count was 552us (39%) at the random-atomic traffic roofline
// (WRITE_SIZE 408.8MB = 12.8M atomics x 32B). Drop the deg atomic: deg is now
// computed FROM the CSR (segment sum of w), and dinv is folded into features
// (g = dinv*h) + per-node epilogues, so no per-edge norm is ever materialized.
// edata stores (row, raw w). Atomics remaining: 6.4M cnt + 6.4M scatter cursor.
// Fallback (ws_size < 65.3 MB) unchanged: atomic scatter-add, 13.2 MB.

#define N_NODES 100000
#define N_EDGES 6400000
#define IN_DIM  128
#define HID     16
#define NCLS    40

// ---- full-path workspace layout (bytes) ----
#define OFF_DINV  0          // float[N]
#define OFF_CNT   400128     // int[N]    (becomes scatter cursor after scan)
#define OFF_OFFS  800256     // int[N+1]
#define OFF_EDATA 1200384    // int2[E]   (row, w-as-int)
#define OFF_H1    52400384   // float[N*16]
#define OFF_HB    58800384   // float[N*16]
#define OFF_BSUM  65200384   // int[98]
#define WS_FULL_NEED 65210000

// ---- fallback workspace layout ----
#define OFF2_DEG 0           // float[N]
#define OFF2_H1  400128      // float[N*16] (aggregation target)
#define OFF2_HB  6800384     // float[N*16] (pre-agg features)

__global__ __launch_bounds__(256) void k_init(int* cnt) {
    int i = blockIdx.x * 256 + threadIdx.x;
    if (i < N_NODES) cnt[i] = 0;
}

__global__ __launch_bounds__(256) void k_count(const int* col, int* cnt) {
    int e = blockIdx.x * 256 + threadIdx.x;           // grid covers E exactly
    atomicAdd(&cnt[col[e]], 1);
}

// ---- 3-kernel exclusive scan of cnt[N] -> offs[N+1] ----
__global__ __launch_bounds__(1024) void k_scan1(const int* cnt, int* offs, int* bsum) {
    __shared__ int s[1024];
    int tid = threadIdx.x;
    int gid = blockIdx.x * 1024 + tid;
    int v = (gid < N_NODES) ? cnt[gid] : 0;
    s[tid] = v;
    __syncthreads();
    for (int o = 1; o < 1024; o <<= 1) {
        int t = (tid >= o) ? s[tid - o] : 0;
        __syncthreads();
        s[tid] += t;
        __syncthreads();
    }
    if (gid < N_NODES) offs[gid] = s[tid] - v;        // block-local exclusive
    if (tid == 1023) bsum[blockIdx.x] = s[1023];
}

__global__ __launch_bounds__(128) void k_scan2(int* bsum) {
    __shared__ int s[128];
    int tid = threadIdx.x;
    int v = (tid < 98) ? bsum[tid] : 0;
    s[tid] = v;
    __syncthreads();
    for (int o = 1; o < 128; o <<= 1) {
        int t = (tid >= o) ? s[tid - o] : 0;
        __syncthreads();
        s[tid] += t;
        __syncthreads();
    }
    if (tid < 98) bsum[tid] = s[tid] - v;             // exclusive block offsets
}

__global__ __launch_bounds__(1024) void k_scan3(int* offs, int* cur, const int* bsum) {
    int tid = threadIdx.x;
    int gid = blockIdx.x * 1024 + tid;
    if (gid < N_NODES) {
        int o = offs[gid] + bsum[blockIdx.x];
        offs[gid] = o;
        cur[gid] = o;                                  // scatter cursor (reuses cnt buf)
    }
    if (gid == 0) offs[N_NODES] = N_EDGES;
}

__global__ __launch_bounds__(256) void k_scatter(const int* row, const int* col,
                                                 const float* w, int* cur, int2* edata) {
    int e = blockIdx.x * 256 + threadIdx.x;           // grid covers E exactly
    int r = row[e];
    int c = col[e];
    int p = atomicAdd(&cur[c], 1);
    edata[p] = make_int2(r, __float_as_int(w[e]));    // raw w; norm folded elsewhere
}

// deg[node] = 1 + sum(w over CSR segment); dinv = 1/sqrt(deg). 16 lanes/node.
__global__ __launch_bounds__(256) void k_deg_dinv(const int* offs, const int2* edata,
                                                  float* dinv) {
    int tid = threadIdx.x;
    int lane = tid & 15;
    int node = blockIdx.x * 16 + (tid >> 4);
    int e0 = offs[node], e1 = offs[node + 1];
    float s = 0.0f;
    for (int e = e0 + lane; e < e1; e += 16)          // coalesced 128B per group-iter
        s += __int_as_float(edata[e].y);
    for (int o = 1; o < 16; o <<= 1) s += __shfl_xor(s, o, 64);
    if (lane == 0) dinv[node] = 1.0f / sqrtf(1.0f + s);
}

// h1 = dinv[node] * (z @ W1)   [100000,128] @ [128,16], dinv-prescaled (g1)
// fallback passes dinv=nullptr -> unscaled.
__global__ __launch_bounds__(256) void k_gemm1(const float* z, const float* W1, float* h1,
                                               const float* dinv) {
    __shared__ float w1s[IN_DIM * HID];               // 8 KB
    __shared__ float zs[64 * 132];                    // 64 rows, pad 128->132 (bank-safe)
    int tid = threadIdx.x;
    for (int i = tid; i < IN_DIM * HID / 4; i += 256)
        ((float4*)w1s)[i] = ((const float4*)W1)[i];
    int nodeBase = blockIdx.x * 64;
    for (int i = tid; i < 64 * 32; i += 256) {        // 2048 float4 loads, coalesced
        int nl = i >> 5, kq = i & 31;
        int node = nodeBase + nl;
        float4 v = (node < N_NODES) ? ((const float4*)z)[node * 32 + kq]
                                    : make_float4(0.f, 0.f, 0.f, 0.f);
        *(float4*)&zs[nl * 132 + kq * 4] = v;
    }
    __syncthreads();
    int nl = tid >> 2;
    int jb = (tid & 3) * 4;
    int node = nodeBase + nl;
    float4 acc = make_float4(0.f, 0.f, 0.f, 0.f);
    for (int k = 0; k < IN_DIM; k++) {
        float s = zs[nl * 132 + k];
        float4 wv = *(const float4*)&w1s[k * HID + jb];
        acc.x += s * wv.x; acc.y += s * wv.y; acc.z += s * wv.z; acc.w += s * wv.w;
    }
    if (node < N_NODES) {
        float dv = dinv ? dinv[node] : 1.0f;
        acc.x *= dv; acc.y *= dv; acc.z *= dv; acc.w *= dv;
        ((float4*)h1)[node * 4 + (tid & 3)] = acc;
    }
}

// conv1 aggregate (+b1, ReLU), fused h2 = x1 @ W2 via in-wave shuffles.
// h1 holds g1 = dinv*(z@W1); x1 = dinv[c]*(g1[c] + sum w*g1[r]) + b1.
// hb stores g2 = dinv[c] * (relu(x1) @ W2) for conv2.
__global__ __launch_bounds__(256) void k_agg1(const float* h1, const float* dinv,
                                              const int* offs, const int2* edata,
                                              const float* b1, const float* W2, float* hb) {
    __shared__ float w2s[HID * HID];
    int tid = threadIdx.x;
    if (tid < HID * HID) w2s[tid] = W2[tid];
    __syncthreads();
    int lane = tid & 15;
    int node = blockIdx.x * 16 + (tid >> 4);
    float acc = h1[node * HID + lane];                // self-loop: g1[c]
    int e0 = offs[node], e1 = offs[node + 1];
    for (int e = e0; e < e1; e++) {
        int2 ed = edata[e];
        acc += __int_as_float(ed.y) * h1[ed.x * HID + lane];   // w * g1[r]
    }
    float d = dinv[node];
    acc = d * acc + b1[lane];
    acc = fmaxf(acc, 0.0f);                           // ReLU
    int base = tid & 48;                              // 16-lane group base in wave
    float h2 = 0.0f;
    for (int k = 0; k < HID; k++) {
        float v = __shfl(acc, base + k, 64);
        h2 += v * w2s[k * HID + lane];
    }
    hb[node * HID + lane] = d * h2;                   // store g2 = dinv*h2
}

// conv2 aggregate (+b2), fused classifier (16->40) + log_softmax, writes d_out.
__global__ __launch_bounds__(256) void k_agg2(const float* hb, const float* dinv,
                                              const int* offs, const int2* edata,
                                              const float* b2, const float* Wc,
                                              const float* bc, float* out) {
    __shared__ float wcs[HID * NCLS];                 // 640 floats
    __shared__ float bcs[NCLS];
    int tid = threadIdx.x;
    for (int i = tid; i < HID * NCLS; i += 256) wcs[i] = Wc[i];
    if (tid < NCLS) bcs[tid] = bc[tid];
    __syncthreads();
    int lane = tid & 15;
    int node = blockIdx.x * 16 + (tid >> 4);
    float acc = hb[node * HID + lane];                // self-loop: g2[c]
    int e0 = offs[node], e1 = offs[node + 1];
    for (int e = e0; e < e1; e++) {
        int2 ed = edata[e];
        acc += __int_as_float(ed.y) * hb[ed.x * HID + lane];   // w * g2[r]
    }
    acc = dinv[node] * acc + b2[lane];
    // classifier: lane j owns logits j, j+16, and j+32 (j<8)
    float l0 = bcs[lane];
    float l1 = bcs[lane + 16];
    float l2 = (lane < 8) ? bcs[lane + 32] : 0.0f;
    int base = tid & 48;
    for (int k = 0; k < HID; k++) {
        float v = __shfl(acc, base + k, 64);
        l0 += v * wcs[k * NCLS + lane];
        l1 += v * wcs[k * NCLS + lane + 16];
        if (lane < 8) l2 += v * wcs[k * NCLS + lane + 32];
    }
    // log_softmax over the 40 values held by this 16-lane group
    float m = fmaxf(l0, l1);
    if (lane < 8) m = fmaxf(m, l2);
    for (int o = 1; o < 16; o <<= 1) m = fmaxf(m, __shfl_xor(m, o, 64));
    float s = expf(l0 - m) + expf(l1 - m) + ((lane < 8) ? expf(l2 - m) : 0.0f);
    for (int o = 1; o < 16; o <<= 1) s += __shfl_xor(s, o, 64);
    float ls = logf(s) + m;
    out[node * NCLS + lane] = l0 - ls;
    out[node * NCLS + lane + 16] = l1 - ls;
    if (lane < 8) out[node * NCLS + lane + 32] = l2 - ls;
}

// ==================== fallback path (small workspace) ====================

__global__ __launch_bounds__(256) void k_init_deg(float* deg) {
    int i = blockIdx.x * 256 + threadIdx.x;
    if (i < N_NODES) deg[i] = 1.0f;
}

__global__ __launch_bounds__(256) void k_deg_only(const int* col, const float* w, float* deg) {
    int e = blockIdx.x * 256 + threadIdx.x;
    atomicAdd(&deg[col[e]], w[e]);
}

__global__ __launch_bounds__(256) void k_dinv(float* deg) {
    int i = blockIdx.x * 256 + threadIdx.x;
    if (i < N_NODES) {
        float d = deg[i];
        deg[i] = (d > 0.0f) ? 1.0f / sqrtf(d) : 0.0f;
    }
}

// agg[i] = dinv[node]^2 * h[i]   (self-loop init), N*16 threads
__global__ __launch_bounds__(256) void k_self(const float* dinv, const float* h, float* agg) {
    int i = blockIdx.x * 256 + threadIdx.x;           // 6250 blocks exact
    float d = dinv[i >> 4];
    agg[i] = d * d * h[i];
}

// one thread per (edge,lane): agg[c*16+l] += norm * h[r*16+l], E*16 threads
__global__ __launch_bounds__(256) void k_edge_atomic(const int* row, const int* col,
                                                     const float* w, const float* dinv,
                                                     const float* h, float* agg) {
    int gid = blockIdx.x * 256 + threadIdx.x;         // 400000 blocks exact
    int e = gid >> 4, lane = gid & 15;
    int r = row[e], c = col[e];
    float nrm = dinv[r] * w[e] * dinv[c];
    atomicAdd(&agg[c * HID + lane], nrm * h[r * HID + lane]);
}

// x2 = relu(agg + b1) @ W2, per-node 16 lanes (shuffle matmul)
__global__ __launch_bounds__(256) void k_bias_relu_gemm2(const float* agg, const float* b1,
                                                         const float* W2, float* out2) {
    __shared__ float w2s[HID * HID];
    int tid = threadIdx.x;
    if (tid < HID * HID) w2s[tid] = W2[tid];
    __syncthreads();
    int lane = tid & 15;
    int node = blockIdx.x * 16 + (tid >> 4);
    float acc = fmaxf(agg[node * HID + lane] + b1[lane], 0.0f);
    int base = tid & 48;
    float h2 = 0.0f;
    for (int k = 0; k < HID; k++) {
        float v = __shfl(acc, base + k, 64);
        h2 += v * w2s[k * HID + lane];
    }
    out2[node * HID + lane] = h2;
}

// out = log_softmax((agg + b2) @ Wc + bc)
__global__ __launch_bounds__(256) void k_final(const float* agg, const float* b2,
                                               const float* Wc, const float* bc, float* out) {
    __shared__ float wcs[HID * NCLS];
    __shared__ float bcs[NCLS];
    int tid = threadIdx.x;
    for (int i = tid; i < HID * NCLS; i += 256) wcs[i] = Wc[i];
    if (tid < NCLS) bcs[tid] = bc[tid];
    __syncthreads();
    int lane = tid & 15;
    int node = blockIdx.x * 16 + (tid >> 4);
    float acc = agg[node * HID + lane] + b2[lane];
    float l0 = bcs[lane];
    float l1 = bcs[lane + 16];
    float l2 = (lane < 8) ? bcs[lane + 32] : 0.0f;
    int base = tid & 48;
    for (int k = 0; k < HID; k++) {
        float v = __shfl(acc, base + k, 64);
        l0 += v * wcs[k * NCLS + lane];
        l1 += v * wcs[k * NCLS + lane + 16];
        if (lane < 8) l2 += v * wcs[k * NCLS + lane + 32];
    }
    float m = fmaxf(l0, l1);
    if (lane < 8) m = fmaxf(m, l2);
    for (int o = 1; o < 16; o <<= 1) m = fmaxf(m, __shfl_xor(m, o, 64));
    float s = expf(l0 - m) + expf(l1 - m) + ((lane < 8) ? expf(l2 - m) : 0.0f);
    for (int o = 1; o < 16; o <<= 1) s += __shfl_xor(s, o, 64);
    float ls = logf(s) + m;
    out[node * NCLS + lane] = l0 - ls;
    out[node * NCLS + lane + 16] = l1 - ls;
    if (lane < 8) out[node * NCLS + lane + 32] = l2 - ls;
}

extern "C" void kernel_launch(void* const* d_in, const int* in_sizes, int n_in,
                              void* d_out, int out_size, void* d_ws, size_t ws_size,
                              hipStream_t stream) {
    const float* z     = (const float*)d_in[0];
    const int*   eidx  = (const int*)d_in[1];       // [2, E] int32
    const float* eattr = (const float*)d_in[2];
    const float* W1    = (const float*)d_in[3];
    const float* b1    = (const float*)d_in[4];
    const float* W2    = (const float*)d_in[5];
    const float* b2    = (const float*)d_in[6];
    const float* Wc    = (const float*)d_in[7];
    const float* bc    = (const float*)d_in[8];
    float* out = (float*)d_out;

    char* ws = (char*)d_ws;
    const int* rowp = eidx;
    const int* colp = eidx + N_EDGES;

    int nblk  = (N_NODES + 255) / 256;              // 391
    int eblk  = N_EDGES / 256;                      // 25000 exact
    int sblk  = (N_NODES + 1023) / 1024;            // 98
    int gblk  = (N_NODES + 63) / 64;                // 1563
    int ablk  = N_NODES / 16;                       // 6250
    int fblk  = (N_NODES * HID) / 256;              // 6250
    int exblk = (N_EDGES * HID) / 256;              // 400000

    if (ws_size >= (size_t)WS_FULL_NEED) {
        // ---------- CSR path ----------
        float* dinv = (float*)(ws + OFF_DINV);
        int*   cnt  = (int*)(ws + OFF_CNT);         // becomes cursor
        int*   offs = (int*)(ws + OFF_OFFS);
        int2*  edat = (int2*)(ws + OFF_EDATA);
        float* h1   = (float*)(ws + OFF_H1);
        float* hb   = (float*)(ws + OFF_HB);
        int*   bsum = (int*)(ws + OFF_BSUM);

        k_init<<<nblk, 256, 0, stream>>>(cnt);
        k_count<<<eblk, 256, 0, stream>>>(colp, cnt);
        k_scan1<<<sblk, 1024, 0, stream>>>(cnt, offs, bsum);
        k_scan2<<<1, 128, 0, stream>>>(bsum);
        k_scan3<<<sblk, 1024, 0, stream>>>(offs, cnt, bsum);
        k_scatter<<<eblk, 256, 0, stream>>>(rowp, colp, eattr, cnt, edat);
        k_deg_dinv<<<ablk, 256, 0, stream>>>(offs, edat, dinv);
        k_gemm1<<<gblk, 256, 0, stream>>>(z, W1, h1, dinv);
        k_agg1<<<ablk, 256, 0, stream>>>(h1, dinv, offs, edat, b1, W2, hb);
        k_agg2<<<ablk, 256, 0, stream>>>(hb, dinv, offs, edat, b2, Wc, bc, out);
    } else {
        // ---------- atomic fallback (13.2 MB) ----------
        float* deg = (float*)(ws + OFF2_DEG);
        float* h1  = (float*)(ws + OFF2_H1);        // aggregation target
        float* hb  = (float*)(ws + OFF2_HB);        // pre-agg features

        k_init_deg<<<nblk, 256, 0, stream>>>(deg);
        k_deg_only<<<eblk, 256, 0, stream>>>(colp, eattr, deg);
        k_dinv<<<nblk, 256, 0, stream>>>(deg);
        k_gemm1<<<gblk, 256, 0, stream>>>(z, W1, hb, nullptr);
        k_self<<<fblk, 256, 0, stream>>>(deg, hb, h1);
        k_edge_atomic<<<exblk, 256, 0, stream>>>(rowp, colp, eattr, deg, hb, h1);
        k_bias_relu_gemm2<<<ablk, 256, 0, stream>>>(h1, b1, W2, hb);
        k_self<<<fblk, 256, 0, stream>>>(deg, hb, h1);
        k_edge_atomic<<<exblk, 256, 0, stream>>>(rowp, colp, eattr, deg, hb, h1);
        k_final<<<ablk, 256, 0, stream>>>(h1, b2, Wc, bc, out);
    }
}

// Round 6
// 735.554 us; speedup vs baseline: 1.9129x; 1.5820x over previous
//
#include <hip/hip_runtime.h>
#include <hip/hip_bf16.h>

// GCN inference: conv1(128->16)+ReLU -> conv2(16->16) -> linear(16->40) -> log_softmax
// R5 post-mortem: k_scatter (520us) + k_count (260us) are at the ~24G sector-op/s
// global-atomic wall (each atomic = 32B memory-side RMW). R6: replace count+scan+
// scatter+deg_dinv with a deterministic two-level counting sort (zero global
// atomics): LDS histogram -> matrix scan -> bucket partition (LDS cursors, L2-merged
// writes) -> per-bucket fine sort (emits CSR offs + dinv). agg/gemm unchanged.
// Tier2 (>=65.3MB): R5 atomic-CSR path. Tier3 (>=13.2MB): edge-atomic fallback.

#define N_NODES 100000
#define N_EDGES 6400000
#define IN_DIM  128
#define HID     16
#define NCLS    40

#define K_BKT   196          // buckets = col>>9, 512 nodes each (last: 160)
#define B_PART  400          // histogram/partition blocks, 16000 edges each
#define CHUNK   16000

// ---- tier-1 workspace layout (bytes) ----
#define OFF_CB    0          // int[197] bucket bases (exclusive scan of totals)
#define OFF_TOT   1024       // int[196] bucket totals
#define OFF_DINV  2048       // float[N]
#define OFF_OFFS  402176     // int[N+1]
#define OFF_HIST  802304     // int[400*196]
#define OFF_EBUF1 1116160    // int2[E] bucket-major edges (dead after bucketsort)
#define OFF_EDATA 52316160   // int2[E] final CSR (row, w)
#define WS_T1_NEED 103600000
// h1/hb overlay the dead ebuf1 region:
#define OFF_H1    OFF_EBUF1              // float[N*16]
#define OFF_HB    (OFF_EBUF1 + 6400000)  // float[N*16]

// ---- tier-2 workspace layout (R5 atomic-CSR path) ----
#define T2_DINV  0
#define T2_CNT   400128
#define T2_OFFS  800256
#define T2_EDATA 1200384
#define T2_H1    52400384
#define T2_HB    58800384
#define T2_BSUM  65200384
#define WS_T2_NEED 65210000

// ---- tier-3 fallback layout ----
#define OFF3_DEG 0
#define OFF3_H1  400128
#define OFF3_HB  6800384

// =================== tier-1: deterministic CSR build ===================

__global__ __launch_bounds__(256) void k_hist(const int* col, int* hist) {
    __shared__ int h[K_BKT];
    int t = threadIdx.x;
    if (t < K_BKT) h[t] = 0;
    __syncthreads();
    int b = blockIdx.x;
    for (int e = b * CHUNK + t; e < (b + 1) * CHUNK; e += 256)
        atomicAdd(&h[col[e] >> 9], 1);                // LDS atomic: no HBM traffic
    __syncthreads();
    if (t < K_BKT) hist[b * K_BKT + t] = h[t];
}

// one block per bucket k: exclusive-scan hist[.][k] over the 400 blocks
__global__ __launch_bounds__(256) void k_colscan(int* hist, int* tot) {
    __shared__ int s[512];
    int t = threadIdx.x;
    int k = blockIdx.x;
    int v0 = (t < B_PART) ? hist[t * K_BKT + k] : 0;
    int v1 = (t + 256 < B_PART) ? hist[(t + 256) * K_BKT + k] : 0;
    s[t] = v0; s[t + 256] = v1;
    __syncthreads();
    for (int o = 1; o < 512; o <<= 1) {
        int a0 = (t >= o) ? s[t - o] : 0;
        int a1 = (t + 256 >= o) ? s[t + 256 - o] : 0;
        __syncthreads();
        s[t] += a0; s[t + 256] += a1;
        __syncthreads();
    }
    if (t < B_PART) hist[t * K_BKT + k] = s[t] - v0;  // exclusive
    if (t + 256 < B_PART) hist[(t + 256) * K_BKT + k] = s[t + 256] - v1;
    if (t == 0) tot[k] = s[B_PART - 1];               // inclusive total
}

__global__ __launch_bounds__(256) void k_basescan(const int* tot, int* cbase) {
    __shared__ int s[256];
    int t = threadIdx.x;
    int v = (t < K_BKT) ? tot[t] : 0;
    s[t] = v;
    __syncthreads();
    for (int o = 1; o < 256; o <<= 1) {
        int a = (t >= o) ? s[t - o] : 0;
        __syncthreads();
        s[t] += a;
        __syncthreads();
    }
    if (t < K_BKT) cbase[t] = s[t] - v;               // exclusive
    if (t == 0) cbase[K_BKT] = N_EDGES;
}

// partition edges into bucket-major ebuf1; packed = row | (col_local<<17)
__global__ __launch_bounds__(256) void k_partition(const int* row, const int* col,
                                                   const float* w, const int* hist,
                                                   const int* cbase, int2* ebuf1) {
    __shared__ int cur[K_BKT];
    int t = threadIdx.x;
    int b = blockIdx.x;
    if (t < K_BKT) cur[t] = cbase[t] + hist[b * K_BKT + t];
    __syncthreads();
    for (int e = b * CHUNK + t; e < (b + 1) * CHUNK; e += 256) {
        int c = col[e];
        int k = c >> 9;
        int p = atomicAdd(&cur[k], 1);                // LDS atomic
        ebuf1[p] = make_int2(row[e] | ((c & 511) << 17), __float_as_int(w[e]));
    }
}

// per-bucket: fine counting sort (512 local nodes) -> edata CSR; also offs + dinv.
__global__ __launch_bounds__(256) void k_bucketsort(const int2* ebuf1, const int* cbase,
                                                    int2* edata, int* offs, float* dinv) {
    __shared__ int   cnt[512];
    __shared__ float degw[512];
    __shared__ int   sc[512];
    __shared__ int   cur[512];
    int t = threadIdx.x;
    int k = blockIdx.x;
    cnt[t] = 0; cnt[t + 256] = 0;
    degw[t] = 0.0f; degw[t + 256] = 0.0f;
    __syncthreads();
    int e0 = cbase[k], e1 = cbase[k + 1];
    for (int e = e0 + t; e < e1; e += 256) {          // pass A: local histogram + deg
        int2 v = ebuf1[e];
        int cl = v.x >> 17;
        atomicAdd(&cnt[cl], 1);
        atomicAdd(&degw[cl], __int_as_float(v.y));
    }
    __syncthreads();
    int c0 = cnt[t], c1 = cnt[t + 256];
    sc[t] = c0; sc[t + 256] = c1;
    __syncthreads();
    for (int o = 1; o < 512; o <<= 1) {               // inclusive scan of 512
        int a0 = (t >= o) ? sc[t - o] : 0;
        int a1 = (t + 256 >= o) ? sc[t + 256 - o] : 0;
        __syncthreads();
        sc[t] += a0; sc[t + 256] += a1;
        __syncthreads();
    }
    // exclusive offsets; emit offs + dinv for this bucket's nodes
    int ex0 = sc[t] - c0, ex1 = sc[t + 256] - c1;
    cur[t] = e0 + ex0; cur[t + 256] = e0 + ex1;
    int node0 = k * 512 + t, node1 = k * 512 + t + 256;
    if (node0 < N_NODES) {
        offs[node0] = e0 + ex0;
        dinv[node0] = rsqrtf(1.0f + degw[t]);
    }
    if (node1 < N_NODES) {
        offs[node1] = e0 + ex1;
        dinv[node1] = rsqrtf(1.0f + degw[t + 256]);
    }
    if (k == 0 && t == 0) offs[N_NODES] = N_EDGES;
    __syncthreads();
    for (int e = e0 + t; e < e1; e += 256) {          // pass B: scatter (L2-local window)
        int2 v = ebuf1[e];
        int cl = v.x >> 17;
        int p = atomicAdd(&cur[cl], 1);               // LDS atomic
        edata[p] = make_int2(v.x & 131071, v.y);
    }
}

// =================== shared compute kernels ===================

// h1 = dinv[node] * (z @ W1); dinv=nullptr -> unscaled (tier-3)
__global__ __launch_bounds__(256) void k_gemm1(const float* z, const float* W1, float* h1,
                                               const float* dinv) {
    __shared__ float w1s[IN_DIM * HID];
    __shared__ float zs[64 * 132];
    int tid = threadIdx.x;
    for (int i = tid; i < IN_DIM * HID / 4; i += 256)
        ((float4*)w1s)[i] = ((const float4*)W1)[i];
    int nodeBase = blockIdx.x * 64;
    for (int i = tid; i < 64 * 32; i += 256) {
        int nl = i >> 5, kq = i & 31;
        int node = nodeBase + nl;
        float4 v = (node < N_NODES) ? ((const float4*)z)[node * 32 + kq]
                                    : make_float4(0.f, 0.f, 0.f, 0.f);
        *(float4*)&zs[nl * 132 + kq * 4] = v;
    }
    __syncthreads();
    int nl = tid >> 2;
    int jb = (tid & 3) * 4;
    int node = nodeBase + nl;
    float4 acc = make_float4(0.f, 0.f, 0.f, 0.f);
    for (int k = 0; k < IN_DIM; k++) {
        float s = zs[nl * 132 + k];
        float4 wv = *(const float4*)&w1s[k * HID + jb];
        acc.x += s * wv.x; acc.y += s * wv.y; acc.z += s * wv.z; acc.w += s * wv.w;
    }
    if (node < N_NODES) {
        float dv = dinv ? dinv[node] : 1.0f;
        acc.x *= dv; acc.y *= dv; acc.z *= dv; acc.w *= dv;
        ((float4*)h1)[node * 4 + (tid & 3)] = acc;
    }
}

// conv1 aggregate (+b1, ReLU), fused h2 = x1 @ W2; hb = dinv * h2
__global__ __launch_bounds__(256) void k_agg1(const float* h1, const float* dinv,
                                              const int* offs, const int2* edata,
                                              const float* b1, const float* W2, float* hb) {
    __shared__ float w2s[HID * HID];
    int tid = threadIdx.x;
    if (tid < HID * HID) w2s[tid] = W2[tid];
    __syncthreads();
    int lane = tid & 15;
    int node = blockIdx.x * 16 + (tid >> 4);
    float acc = h1[node * HID + lane];
    int e0 = offs[node], e1 = offs[node + 1];
    for (int e = e0; e < e1; e++) {
        int2 ed = edata[e];
        acc += __int_as_float(ed.y) * h1[ed.x * HID + lane];
    }
    float d = dinv[node];
    acc = d * acc + b1[lane];
    acc = fmaxf(acc, 0.0f);
    int base = tid & 48;
    float h2 = 0.0f;
    for (int k = 0; k < HID; k++) {
        float v = __shfl(acc, base + k, 64);
        h2 += v * w2s[k * HID + lane];
    }
    hb[node * HID + lane] = d * h2;
}

// conv2 aggregate (+b2), classifier (16->40) + log_softmax
__global__ __launch_bounds__(256) void k_agg2(const float* hb, const float* dinv,
                                              const int* offs, const int2* edata,
                                              const float* b2, const float* Wc,
                                              const float* bc, float* out) {
    __shared__ float wcs[HID * NCLS];
    __shared__ float bcs[NCLS];
    int tid = threadIdx.x;
    for (int i = tid; i < HID * NCLS; i += 256) wcs[i] = Wc[i];
    if (tid < NCLS) bcs[tid] = bc[tid];
    __syncthreads();
    int lane = tid & 15;
    int node = blockIdx.x * 16 + (tid >> 4);
    float acc = hb[node * HID + lane];
    int e0 = offs[node], e1 = offs[node + 1];
    for (int e = e0; e < e1; e++) {
        int2 ed = edata[e];
        acc += __int_as_float(ed.y) * hb[ed.x * HID + lane];
    }
    acc = dinv[node] * acc + b2[lane];
    float l0 = bcs[lane];
    float l1 = bcs[lane + 16];
    float l2 = (lane < 8) ? bcs[lane + 32] : 0.0f;
    int base = tid & 48;
    for (int k = 0; k < HID; k++) {
        float v = __shfl(acc, base + k, 64);
        l0 += v * wcs[k * NCLS + lane];
        l1 += v * wcs[k * NCLS + lane + 16];
        if (lane < 8) l2 += v * wcs[k * NCLS + lane + 32];
    }
    float m = fmaxf(l0, l1);
    if (lane < 8) m = fmaxf(m, l2);
    for (int o = 1; o < 16; o <<= 1) m = fmaxf(m, __shfl_xor(m, o, 64));
    float s = expf(l0 - m) + expf(l1 - m) + ((lane < 8) ? expf(l2 - m) : 0.0f);
    for (int o = 1; o < 16; o <<= 1) s += __shfl_xor(s, o, 64);
    float ls = logf(s) + m;
    out[node * NCLS + lane] = l0 - ls;
    out[node * NCLS + lane + 16] = l1 - ls;
    if (lane < 8) out[node * NCLS + lane + 32] = l2 - ls;
}

// =================== tier-2: R5 atomic-CSR build ===================

__global__ __launch_bounds__(256) void k_init(int* cnt) {
    int i = blockIdx.x * 256 + threadIdx.x;
    if (i < N_NODES) cnt[i] = 0;
}

__global__ __launch_bounds__(256) void k_count(const int* col, int* cnt) {
    int e = blockIdx.x * 256 + threadIdx.x;
    atomicAdd(&cnt[col[e]], 1);
}

__global__ __launch_bounds__(1024) void k_scan1(const int* cnt, int* offs, int* bsum) {
    __shared__ int s[1024];
    int tid = threadIdx.x;
    int gid = blockIdx.x * 1024 + tid;
    int v = (gid < N_NODES) ? cnt[gid] : 0;
    s[tid] = v;
    __syncthreads();
    for (int o = 1; o < 1024; o <<= 1) {
        int t = (tid >= o) ? s[tid - o] : 0;
        __syncthreads();
        s[tid] += t;
        __syncthreads();
    }
    if (gid < N_NODES) offs[gid] = s[tid] - v;
    if (tid == 1023) bsum[blockIdx.x] = s[1023];
}

__global__ __launch_bounds__(128) void k_scan2(int* bsum) {
    __shared__ int s[128];
    int tid = threadIdx.x;
    int v = (tid < 98) ? bsum[tid] : 0;
    s[tid] = v;
    __syncthreads();
    for (int o = 1; o < 128; o <<= 1) {
        int t = (tid >= o) ? s[tid - o] : 0;
        __syncthreads();
        s[tid] += t;
        __syncthreads();
    }
    if (tid < 98) bsum[tid] = s[tid] - v;
}

__global__ __launch_bounds__(1024) void k_scan3(int* offs, int* cur, const int* bsum) {
    int tid = threadIdx.x;
    int gid = blockIdx.x * 1024 + tid;
    if (gid < N_NODES) {
        int o = offs[gid] + bsum[blockIdx.x];
        offs[gid] = o;
        cur[gid] = o;
    }
    if (gid == 0) offs[N_NODES] = N_EDGES;
}

__global__ __launch_bounds__(256) void k_scatter(const int* row, const int* col,
                                                 const float* w, int* cur, int2* edata) {
    int e = blockIdx.x * 256 + threadIdx.x;
    int r = row[e];
    int c = col[e];
    int p = atomicAdd(&cur[c], 1);
    edata[p] = make_int2(r, __float_as_int(w[e]));
}

__global__ __launch_bounds__(256) void k_deg_dinv(const int* offs, const int2* edata,
                                                  float* dinv) {
    int tid = threadIdx.x;
    int lane = tid & 15;
    int node = blockIdx.x * 16 + (tid >> 4);
    int e0 = offs[node], e1 = offs[node + 1];
    float s = 0.0f;
    for (int e = e0 + lane; e < e1; e += 16)
        s += __int_as_float(edata[e].y);
    for (int o = 1; o < 16; o <<= 1) s += __shfl_xor(s, o, 64);
    if (lane == 0) dinv[node] = 1.0f / sqrtf(1.0f + s);
}

// =================== tier-3: edge-atomic fallback ===================

__global__ __launch_bounds__(256) void k_init_deg(float* deg) {
    int i = blockIdx.x * 256 + threadIdx.x;
    if (i < N_NODES) deg[i] = 1.0f;
}

__global__ __launch_bounds__(256) void k_deg_only(const int* col, const float* w, float* deg) {
    int e = blockIdx.x * 256 + threadIdx.x;
    atomicAdd(&deg[col[e]], w[e]);
}

__global__ __launch_bounds__(256) void k_dinv(float* deg) {
    int i = blockIdx.x * 256 + threadIdx.x;
    if (i < N_NODES) {
        float d = deg[i];
        deg[i] = (d > 0.0f) ? 1.0f / sqrtf(d) : 0.0f;
    }
}

__global__ __launch_bounds__(256) void k_self(const float* dinv, const float* h, float* agg) {
    int i = blockIdx.x * 256 + threadIdx.x;
    float d = dinv[i >> 4];
    agg[i] = d * d * h[i];
}

__global__ __launch_bounds__(256) void k_edge_atomic(const int* row, const int* col,
                                                     const float* w, const float* dinv,
                                                     const float* h, float* agg) {
    int gid = blockIdx.x * 256 + threadIdx.x;
    int e = gid >> 4, lane = gid & 15;
    int r = row[e], c = col[e];
    float nrm = dinv[r] * w[e] * dinv[c];
    atomicAdd(&agg[c * HID + lane], nrm * h[r * HID + lane]);
}

__global__ __launch_bounds__(256) void k_bias_relu_gemm2(const float* agg, const float* b1,
                                                         const float* W2, float* out2) {
    __shared__ float w2s[HID * HID];
    int tid = threadIdx.x;
    if (tid < HID * HID) w2s[tid] = W2[tid];
    __syncthreads();
    int lane = tid & 15;
    int node = blockIdx.x * 16 + (tid >> 4);
    float acc = fmaxf(agg[node * HID + lane] + b1[lane], 0.0f);
    int base = tid & 48;
    float h2 = 0.0f;
    for (int k = 0; k < HID; k++) {
        float v = __shfl(acc, base + k, 64);
        h2 += v * w2s[k * HID + lane];
    }
    out2[node * HID + lane] = h2;
}

__global__ __launch_bounds__(256) void k_final(const float* agg, const float* b2,
                                               const float* Wc, const float* bc, float* out) {
    __shared__ float wcs[HID * NCLS];
    __shared__ float bcs[NCLS];
    int tid = threadIdx.x;
    for (int i = tid; i < HID * NCLS; i += 256) wcs[i] = Wc[i];
    if (tid < NCLS) bcs[tid] = bc[tid];
    __syncthreads();
    int lane = tid & 15;
    int node = blockIdx.x * 16 + (tid >> 4);
    float acc = agg[node * HID + lane] + b2[lane];
    float l0 = bcs[lane];
    float l1 = bcs[lane + 16];
    float l2 = (lane < 8) ? bcs[lane + 32] : 0.0f;
    int base = tid & 48;
    for (int k = 0; k < HID; k++) {
        float v = __shfl(acc, base + k, 64);
        l0 += v * wcs[k * NCLS + lane];
        l1 += v * wcs[k * NCLS + lane + 16];
        if (lane < 8) l2 += v * wcs[k * NCLS + lane + 32];
    }
    float m = fmaxf(l0, l1);
    if (lane < 8) m = fmaxf(m, l2);
    for (int o = 1; o < 16; o <<= 1) m = fmaxf(m, __shfl_xor(m, o, 64));
    float s = expf(l0 - m) + expf(l1 - m) + ((lane < 8) ? expf(l2 - m) : 0.0f);
    for (int o = 1; o < 16; o <<= 1) s += __shfl_xor(s, o, 64);
    float ls = logf(s) + m;
    out[node * NCLS + lane] = l0 - ls;
    out[node * NCLS + lane + 16] = l1 - ls;
    if (lane < 8) out[node * NCLS + lane + 32] = l2 - ls;
}

extern "C" void kernel_launch(void* const* d_in, const int* in_sizes, int n_in,
                              void* d_out, int out_size, void* d_ws, size_t ws_size,
                              hipStream_t stream) {
    const float* z     = (const float*)d_in[0];
    const int*   eidx  = (const int*)d_in[1];
    const float* eattr = (const float*)d_in[2];
    const float* W1    = (const float*)d_in[3];
    const float* b1    = (const float*)d_in[4];
    const float* W2    = (const float*)d_in[5];
    const float* b2    = (const float*)d_in[6];
    const float* Wc    = (const float*)d_in[7];
    const float* bc    = (const float*)d_in[8];
    float* out = (float*)d_out;

    char* ws = (char*)d_ws;
    const int* rowp = eidx;
    const int* colp = eidx + N_EDGES;

    int nblk = (N_NODES + 255) / 256;               // 391
    int eblk = N_EDGES / 256;                       // 25000
    int sblk = (N_NODES + 1023) / 1024;             // 98
    int gblk = (N_NODES + 63) / 64;                 // 1563
    int ablk = N_NODES / 16;                        // 6250
    int fblk = (N_NODES * HID) / 256;               // 6250
    int exblk = (N_EDGES * HID) / 256;              // 400000

    if (ws_size >= (size_t)WS_T1_NEED) {
        // ---------- tier-1: atomic-free CSR build ----------
        int*   cbase = (int*)(ws + OFF_CB);
        int*   tot   = (int*)(ws + OFF_TOT);
        float* dinv  = (float*)(ws + OFF_DINV);
        int*   offs  = (int*)(ws + OFF_OFFS);
        int*   hist  = (int*)(ws + OFF_HIST);
        int2*  ebuf1 = (int2*)(ws + OFF_EBUF1);
        int2*  edat  = (int2*)(ws + OFF_EDATA);
        float* h1    = (float*)(ws + OFF_H1);
        float* hb    = (float*)(ws + OFF_HB);

        k_hist<<<B_PART, 256, 0, stream>>>(colp, hist);
        k_colscan<<<K_BKT, 256, 0, stream>>>(hist, tot);
        k_basescan<<<1, 256, 0, stream>>>(tot, cbase);
        k_partition<<<B_PART, 256, 0, stream>>>(rowp, colp, eattr, hist, cbase, ebuf1);
        k_bucketsort<<<K_BKT, 256, 0, stream>>>(ebuf1, cbase, edat, offs, dinv);
        k_gemm1<<<gblk, 256, 0, stream>>>(z, W1, h1, dinv);      // h1 overlays dead ebuf1
        k_agg1<<<ablk, 256, 0, stream>>>(h1, dinv, offs, edat, b1, W2, hb);
        k_agg2<<<ablk, 256, 0, stream>>>(hb, dinv, offs, edat, b2, Wc, bc, out);
    } else if (ws_size >= (size_t)WS_T2_NEED) {
        // ---------- tier-2: atomic-CSR path (R5) ----------
        float* dinv = (float*)(ws + T2_DINV);
        int*   cnt  = (int*)(ws + T2_CNT);
        int*   offs = (int*)(ws + T2_OFFS);
        int2*  edat = (int2*)(ws + T2_EDATA);
        float* h1   = (float*)(ws + T2_H1);
        float* hb   = (float*)(ws + T2_HB);
        int*   bsum = (int*)(ws + T2_BSUM);

        k_init<<<nblk, 256, 0, stream>>>(cnt);
        k_count<<<eblk, 256, 0, stream>>>(colp, cnt);
        k_scan1<<<sblk, 1024, 0, stream>>>(cnt, offs, bsum);
        k_scan2<<<1, 128, 0, stream>>>(bsum);
        k_scan3<<<sblk, 1024, 0, stream>>>(offs, cnt, bsum);
        k_scatter<<<eblk, 256, 0, stream>>>(rowp, colp, eattr, cnt, edat);
        k_deg_dinv<<<ablk, 256, 0, stream>>>(offs, edat, dinv);
        k_gemm1<<<gblk, 256, 0, stream>>>(z, W1, h1, dinv);
        k_agg1<<<ablk, 256, 0, stream>>>(h1, dinv, offs, edat, b1, W2, hb);
        k_agg2<<<ablk, 256, 0, stream>>>(hb, dinv, offs, edat, b2, Wc, bc, out);
    } else {
        // ---------- tier-3: edge-atomic fallback ----------
        float* deg = (float*)(ws + OFF3_DEG);
        float* h1  = (float*)(ws + OFF3_H1);
        float* hb  = (float*)(ws + OFF3_HB);

        k_init_deg<<<nblk, 256, 0, stream>>>(deg);
        k_deg_only<<<eblk, 256, 0, stream>>>(colp, eattr, deg);
        k_dinv<<<nblk, 256, 0, stream>>>(deg);
        k_gemm1<<<gblk, 256, 0, stream>>>(z, W1, hb, nullptr);
        k_self<<<fblk, 256, 0, stream>>>(deg, hb, h1);
        k_edge_atomic<<<exblk, 256, 0, stream>>>(rowp, colp, eattr, deg, hb, h1);
        k_bias_relu_gemm2<<<ablk, 256, 0, stream>>>(h1, b1, W2, hb);
        k_self<<<fblk, 256, 0, stream>>>(deg, hb, h1);
        k_edge_atomic<<<exblk, 256, 0, stream>>>(rowp, colp, eattr, deg, hb, h1);
        k_final<<<ablk, 256, 0, stream>>>(h1, b2, Wc, bc, out);
    }
}

// Round 7
// 530.664 us; speedup vs baseline: 2.6515x; 1.3861x over previous
//
#include <hip/hip_runtime.h>
#include <hip/hip_bf16.h>

// GCN inference: conv1(128->16)+ReLU -> conv2(16->16) -> linear(16->40) -> log_softmax
// R6 post-mortem: atomic-free CSR build works (1164->736us). Top kernel now
// k_agg1/k_agg2 (~185us each), latency-bound: VALUBusy 15%, HBM 16%, occupancy 70%
// -> ~1 outstanding gather per 16-lane group (serial edata->gather dep chain).
// R7: unroll the edge loop 8x -> 8 independent edata loads + 8 independent
// gathers in flight per group. Everything else unchanged.

#define N_NODES 100000
#define N_EDGES 6400000
#define IN_DIM  128
#define HID     16
#define NCLS    40

#define K_BKT   196          // buckets = col>>9, 512 nodes each (last: 160)
#define B_PART  400          // histogram/partition blocks, 16000 edges each
#define CHUNK   16000

// ---- tier-1 workspace layout (bytes) ----
#define OFF_CB    0          // int[197] bucket bases (exclusive scan of totals)
#define OFF_TOT   1024       // int[196] bucket totals
#define OFF_DINV  2048       // float[N]
#define OFF_OFFS  402176     // int[N+1]
#define OFF_HIST  802304     // int[400*196]
#define OFF_EBUF1 1116160    // int2[E] bucket-major edges (dead after bucketsort)
#define OFF_EDATA 52316160   // int2[E] final CSR (row, w)
#define WS_T1_NEED 103600000
// h1/hb overlay the dead ebuf1 region:
#define OFF_H1    OFF_EBUF1              // float[N*16]
#define OFF_HB    (OFF_EBUF1 + 6400000)  // float[N*16]

// ---- tier-2 workspace layout (R5 atomic-CSR path) ----
#define T2_DINV  0
#define T2_CNT   400128
#define T2_OFFS  800256
#define T2_EDATA 1200384
#define T2_H1    52400384
#define T2_HB    58800384
#define T2_BSUM  65200384
#define WS_T2_NEED 65210000

// ---- tier-3 fallback layout ----
#define OFF3_DEG 0
#define OFF3_H1  400128
#define OFF3_HB  6800384

// =================== tier-1: deterministic CSR build ===================

__global__ __launch_bounds__(256) void k_hist(const int* col, int* hist) {
    __shared__ int h[K_BKT];
    int t = threadIdx.x;
    if (t < K_BKT) h[t] = 0;
    __syncthreads();
    int b = blockIdx.x;
    for (int e = b * CHUNK + t; e < (b + 1) * CHUNK; e += 256)
        atomicAdd(&h[col[e] >> 9], 1);                // LDS atomic: no HBM traffic
    __syncthreads();
    if (t < K_BKT) hist[b * K_BKT + t] = h[t];
}

// one block per bucket k: exclusive-scan hist[.][k] over the 400 blocks
__global__ __launch_bounds__(256) void k_colscan(int* hist, int* tot) {
    __shared__ int s[512];
    int t = threadIdx.x;
    int k = blockIdx.x;
    int v0 = (t < B_PART) ? hist[t * K_BKT + k] : 0;
    int v1 = (t + 256 < B_PART) ? hist[(t + 256) * K_BKT + k] : 0;
    s[t] = v0; s[t + 256] = v1;
    __syncthreads();
    for (int o = 1; o < 512; o <<= 1) {
        int a0 = (t >= o) ? s[t - o] : 0;
        int a1 = (t + 256 >= o) ? s[t + 256 - o] : 0;
        __syncthreads();
        s[t] += a0; s[t + 256] += a1;
        __syncthreads();
    }
    if (t < B_PART) hist[t * K_BKT + k] = s[t] - v0;  // exclusive
    if (t + 256 < B_PART) hist[(t + 256) * K_BKT + k] = s[t + 256] - v1;
    if (t == 0) tot[k] = s[B_PART - 1];               // inclusive total
}

__global__ __launch_bounds__(256) void k_basescan(const int* tot, int* cbase) {
    __shared__ int s[256];
    int t = threadIdx.x;
    int v = (t < K_BKT) ? tot[t] : 0;
    s[t] = v;
    __syncthreads();
    for (int o = 1; o < 256; o <<= 1) {
        int a = (t >= o) ? s[t - o] : 0;
        __syncthreads();
        s[t] += a;
        __syncthreads();
    }
    if (t < K_BKT) cbase[t] = s[t] - v;               // exclusive
    if (t == 0) cbase[K_BKT] = N_EDGES;
}

// partition edges into bucket-major ebuf1; packed = row | (col_local<<17)
__global__ __launch_bounds__(256) void k_partition(const int* row, const int* col,
                                                   const float* w, const int* hist,
                                                   const int* cbase, int2* ebuf1) {
    __shared__ int cur[K_BKT];
    int t = threadIdx.x;
    int b = blockIdx.x;
    if (t < K_BKT) cur[t] = cbase[t] + hist[b * K_BKT + t];
    __syncthreads();
    for (int e = b * CHUNK + t; e < (b + 1) * CHUNK; e += 256) {
        int c = col[e];
        int k = c >> 9;
        int p = atomicAdd(&cur[k], 1);                // LDS atomic
        ebuf1[p] = make_int2(row[e] | ((c & 511) << 17), __float_as_int(w[e]));
    }
}

// per-bucket: fine counting sort (512 local nodes) -> edata CSR; also offs + dinv.
__global__ __launch_bounds__(256) void k_bucketsort(const int2* ebuf1, const int* cbase,
                                                    int2* edata, int* offs, float* dinv) {
    __shared__ int   cnt[512];
    __shared__ float degw[512];
    __shared__ int   sc[512];
    __shared__ int   cur[512];
    int t = threadIdx.x;
    int k = blockIdx.x;
    cnt[t] = 0; cnt[t + 256] = 0;
    degw[t] = 0.0f; degw[t + 256] = 0.0f;
    __syncthreads();
    int e0 = cbase[k], e1 = cbase[k + 1];
    for (int e = e0 + t; e < e1; e += 256) {          // pass A: local histogram + deg
        int2 v = ebuf1[e];
        int cl = v.x >> 17;
        atomicAdd(&cnt[cl], 1);
        atomicAdd(&degw[cl], __int_as_float(v.y));
    }
    __syncthreads();
    int c0 = cnt[t], c1 = cnt[t + 256];
    sc[t] = c0; sc[t + 256] = c1;
    __syncthreads();
    for (int o = 1; o < 512; o <<= 1) {               // inclusive scan of 512
        int a0 = (t >= o) ? sc[t - o] : 0;
        int a1 = (t + 256 >= o) ? sc[t + 256 - o] : 0;
        __syncthreads();
        sc[t] += a0; sc[t + 256] += a1;
        __syncthreads();
    }
    // exclusive offsets; emit offs + dinv for this bucket's nodes
    int ex0 = sc[t] - c0, ex1 = sc[t + 256] - c1;
    cur[t] = e0 + ex0; cur[t + 256] = e0 + ex1;
    int node0 = k * 512 + t, node1 = k * 512 + t + 256;
    if (node0 < N_NODES) {
        offs[node0] = e0 + ex0;
        dinv[node0] = rsqrtf(1.0f + degw[t]);
    }
    if (node1 < N_NODES) {
        offs[node1] = e0 + ex1;
        dinv[node1] = rsqrtf(1.0f + degw[t + 256]);
    }
    if (k == 0 && t == 0) offs[N_NODES] = N_EDGES;
    __syncthreads();
    for (int e = e0 + t; e < e1; e += 256) {          // pass B: scatter (L2-local window)
        int2 v = ebuf1[e];
        int cl = v.x >> 17;
        int p = atomicAdd(&cur[cl], 1);               // LDS atomic
        edata[p] = make_int2(v.x & 131071, v.y);
    }
}

// =================== shared compute kernels ===================

// h1 = dinv[node] * (z @ W1); dinv=nullptr -> unscaled (tier-3)
__global__ __launch_bounds__(256) void k_gemm1(const float* z, const float* W1, float* h1,
                                               const float* dinv) {
    __shared__ float w1s[IN_DIM * HID];
    __shared__ float zs[64 * 132];
    int tid = threadIdx.x;
    for (int i = tid; i < IN_DIM * HID / 4; i += 256)
        ((float4*)w1s)[i] = ((const float4*)W1)[i];
    int nodeBase = blockIdx.x * 64;
    for (int i = tid; i < 64 * 32; i += 256) {
        int nl = i >> 5, kq = i & 31;
        int node = nodeBase + nl;
        float4 v = (node < N_NODES) ? ((const float4*)z)[node * 32 + kq]
                                    : make_float4(0.f, 0.f, 0.f, 0.f);
        *(float4*)&zs[nl * 132 + kq * 4] = v;
    }
    __syncthreads();
    int nl = tid >> 2;
    int jb = (tid & 3) * 4;
    int node = nodeBase + nl;
    float4 acc = make_float4(0.f, 0.f, 0.f, 0.f);
    for (int k = 0; k < IN_DIM; k++) {
        float s = zs[nl * 132 + k];
        float4 wv = *(const float4*)&w1s[k * HID + jb];
        acc.x += s * wv.x; acc.y += s * wv.y; acc.z += s * wv.z; acc.w += s * wv.w;
    }
    if (node < N_NODES) {
        float dv = dinv ? dinv[node] : 1.0f;
        acc.x *= dv; acc.y *= dv; acc.z *= dv; acc.w *= dv;
        ((float4*)h1)[node * 4 + (tid & 3)] = acc;
    }
}

// 8x-unrolled CSR edge aggregation: 8 independent edata loads + 8 independent
// gathers in flight per 16-lane group (was 1 -> latency-bound at 185us).
__device__ __forceinline__ float edge_agg(const float* __restrict__ h,
                                          const int2* __restrict__ edata,
                                          int e0, int e1, int lane, float acc) {
    int e = e0;
    for (; e + 8 <= e1; e += 8) {
        int2 d0 = edata[e];
        int2 d1 = edata[e + 1];
        int2 d2 = edata[e + 2];
        int2 d3 = edata[e + 3];
        int2 d4 = edata[e + 4];
        int2 d5 = edata[e + 5];
        int2 d6 = edata[e + 6];
        int2 d7 = edata[e + 7];
        float g0 = h[d0.x * HID + lane];
        float g1 = h[d1.x * HID + lane];
        float g2 = h[d2.x * HID + lane];
        float g3 = h[d3.x * HID + lane];
        float g4 = h[d4.x * HID + lane];
        float g5 = h[d5.x * HID + lane];
        float g6 = h[d6.x * HID + lane];
        float g7 = h[d7.x * HID + lane];
        acc += __int_as_float(d0.y) * g0;
        acc += __int_as_float(d1.y) * g1;
        acc += __int_as_float(d2.y) * g2;
        acc += __int_as_float(d3.y) * g3;
        acc += __int_as_float(d4.y) * g4;
        acc += __int_as_float(d5.y) * g5;
        acc += __int_as_float(d6.y) * g6;
        acc += __int_as_float(d7.y) * g7;
    }
    for (; e < e1; e++) {
        int2 ed = edata[e];
        acc += __int_as_float(ed.y) * h[ed.x * HID + lane];
    }
    return acc;
}

// conv1 aggregate (+b1, ReLU), fused h2 = x1 @ W2; hb = dinv * h2
__global__ __launch_bounds__(256) void k_agg1(const float* h1, const float* dinv,
                                              const int* offs, const int2* edata,
                                              const float* b1, const float* W2, float* hb) {
    __shared__ float w2s[HID * HID];
    int tid = threadIdx.x;
    if (tid < HID * HID) w2s[tid] = W2[tid];
    __syncthreads();
    int lane = tid & 15;
    int node = blockIdx.x * 16 + (tid >> 4);
    int e0 = offs[node], e1 = offs[node + 1];
    float acc = edge_agg(h1, edata, e0, e1, lane, h1[node * HID + lane]);
    float d = dinv[node];
    acc = d * acc + b1[lane];
    acc = fmaxf(acc, 0.0f);
    int base = tid & 48;
    float h2 = 0.0f;
    for (int k = 0; k < HID; k++) {
        float v = __shfl(acc, base + k, 64);
        h2 += v * w2s[k * HID + lane];
    }
    hb[node * HID + lane] = d * h2;
}

// conv2 aggregate (+b2), classifier (16->40) + log_softmax
__global__ __launch_bounds__(256) void k_agg2(const float* hb, const float* dinv,
                                              const int* offs, const int2* edata,
                                              const float* b2, const float* Wc,
                                              const float* bc, float* out) {
    __shared__ float wcs[HID * NCLS];
    __shared__ float bcs[NCLS];
    int tid = threadIdx.x;
    for (int i = tid; i < HID * NCLS; i += 256) wcs[i] = Wc[i];
    if (tid < NCLS) bcs[tid] = bc[tid];
    __syncthreads();
    int lane = tid & 15;
    int node = blockIdx.x * 16 + (tid >> 4);
    int e0 = offs[node], e1 = offs[node + 1];
    float acc = edge_agg(hb, edata, e0, e1, lane, hb[node * HID + lane]);
    acc = dinv[node] * acc + b2[lane];
    float l0 = bcs[lane];
    float l1 = bcs[lane + 16];
    float l2 = (lane < 8) ? bcs[lane + 32] : 0.0f;
    int base = tid & 48;
    for (int k = 0; k < HID; k++) {
        float v = __shfl(acc, base + k, 64);
        l0 += v * wcs[k * NCLS + lane];
        l1 += v * wcs[k * NCLS + lane + 16];
        if (lane < 8) l2 += v * wcs[k * NCLS + lane + 32];
    }
    float m = fmaxf(l0, l1);
    if (lane < 8) m = fmaxf(m, l2);
    for (int o = 1; o < 16; o <<= 1) m = fmaxf(m, __shfl_xor(m, o, 64));
    float s = expf(l0 - m) + expf(l1 - m) + ((lane < 8) ? expf(l2 - m) : 0.0f);
    for (int o = 1; o < 16; o <<= 1) s += __shfl_xor(s, o, 64);
    float ls = logf(s) + m;
    out[node * NCLS + lane] = l0 - ls;
    out[node * NCLS + lane + 16] = l1 - ls;
    if (lane < 8) out[node * NCLS + lane + 32] = l2 - ls;
}

// =================== tier-2: R5 atomic-CSR build ===================

__global__ __launch_bounds__(256) void k_init(int* cnt) {
    int i = blockIdx.x * 256 + threadIdx.x;
    if (i < N_NODES) cnt[i] = 0;
}

__global__ __launch_bounds__(256) void k_count(const int* col, int* cnt) {
    int e = blockIdx.x * 256 + threadIdx.x;
    atomicAdd(&cnt[col[e]], 1);
}

__global__ __launch_bounds__(1024) void k_scan1(const int* cnt, int* offs, int* bsum) {
    __shared__ int s[1024];
    int tid = threadIdx.x;
    int gid = blockIdx.x * 1024 + tid;
    int v = (gid < N_NODES) ? cnt[gid] : 0;
    s[tid] = v;
    __syncthreads();
    for (int o = 1; o < 1024; o <<= 1) {
        int t = (tid >= o) ? s[tid - o] : 0;
        __syncthreads();
        s[tid] += t;
        __syncthreads();
    }
    if (gid < N_NODES) offs[gid] = s[tid] - v;
    if (tid == 1023) bsum[blockIdx.x] = s[1023];
}

__global__ __launch_bounds__(128) void k_scan2(int* bsum) {
    __shared__ int s[128];
    int tid = threadIdx.x;
    int v = (tid < 98) ? bsum[tid] : 0;
    s[tid] = v;
    __syncthreads();
    for (int o = 1; o < 128; o <<= 1) {
        int t = (tid >= o) ? s[tid - o] : 0;
        __syncthreads();
        s[tid] += t;
        __syncthreads();
    }
    if (tid < 98) bsum[tid] = s[tid] - v;
}

__global__ __launch_bounds__(1024) void k_scan3(int* offs, int* cur, const int* bsum) {
    int tid = threadIdx.x;
    int gid = blockIdx.x * 1024 + tid;
    if (gid < N_NODES) {
        int o = offs[gid] + bsum[blockIdx.x];
        offs[gid] = o;
        cur[gid] = o;
    }
    if (gid == 0) offs[N_NODES] = N_EDGES;
}

__global__ __launch_bounds__(256) void k_scatter(const int* row, const int* col,
                                                 const float* w, int* cur, int2* edata) {
    int e = blockIdx.x * 256 + threadIdx.x;
    int r = row[e];
    int c = col[e];
    int p = atomicAdd(&cur[c], 1);
    edata[p] = make_int2(r, __float_as_int(w[e]));
}

__global__ __launch_bounds__(256) void k_deg_dinv(const int* offs, const int2* edata,
                                                  float* dinv) {
    int tid = threadIdx.x;
    int lane = tid & 15;
    int node = blockIdx.x * 16 + (tid >> 4);
    int e0 = offs[node], e1 = offs[node + 1];
    float s = 0.0f;
    for (int e = e0 + lane; e < e1; e += 16)
        s += __int_as_float(edata[e].y);
    for (int o = 1; o < 16; o <<= 1) s += __shfl_xor(s, o, 64);
    if (lane == 0) dinv[node] = 1.0f / sqrtf(1.0f + s);
}

// =================== tier-3: edge-atomic fallback ===================

__global__ __launch_bounds__(256) void k_init_deg(float* deg) {
    int i = blockIdx.x * 256 + threadIdx.x;
    if (i < N_NODES) deg[i] = 1.0f;
}

__global__ __launch_bounds__(256) void k_deg_only(const int* col, const float* w, float* deg) {
    int e = blockIdx.x * 256 + threadIdx.x;
    atomicAdd(&deg[col[e]], w[e]);
}

__global__ __launch_bounds__(256) void k_dinv(float* deg) {
    int i = blockIdx.x * 256 + threadIdx.x;
    if (i < N_NODES) {
        float d = deg[i];
        deg[i] = (d > 0.0f) ? 1.0f / sqrtf(d) : 0.0f;
    }
}

__global__ __launch_bounds__(256) void k_self(const float* dinv, const float* h, float* agg) {
    int i = blockIdx.x * 256 + threadIdx.x;
    float d = dinv[i >> 4];
    agg[i] = d * d * h[i];
}

__global__ __launch_bounds__(256) void k_edge_atomic(const int* row, const int* col,
                                                     const float* w, const float* dinv,
                                                     const float* h, float* agg) {
    int gid = blockIdx.x * 256 + threadIdx.x;
    int e = gid >> 4, lane = gid & 15;
    int r = row[e], c = col[e];
    float nrm = dinv[r] * w[e] * dinv[c];
    atomicAdd(&agg[c * HID + lane], nrm * h[r * HID + lane]);
}

__global__ __launch_bounds__(256) void k_bias_relu_gemm2(const float* agg, const float* b1,
                                                         const float* W2, float* out2) {
    __shared__ float w2s[HID * HID];
    int tid = threadIdx.x;
    if (tid < HID * HID) w2s[tid] = W2[tid];
    __syncthreads();
    int lane = tid & 15;
    int node = blockIdx.x * 16 + (tid >> 4);
    float acc = fmaxf(agg[node * HID + lane] + b1[lane], 0.0f);
    int base = tid & 48;
    float h2 = 0.0f;
    for (int k = 0; k < HID; k++) {
        float v = __shfl(acc, base + k, 64);
        h2 += v * w2s[k * HID + lane];
    }
    out2[node * HID + lane] = h2;
}

__global__ __launch_bounds__(256) void k_final(const float* agg, const float* b2,
                                               const float* Wc, const float* bc, float* out) {
    __shared__ float wcs[HID * NCLS];
    __shared__ float bcs[NCLS];
    int tid = threadIdx.x;
    for (int i = tid; i < HID * NCLS; i += 256) wcs[i] = Wc[i];
    if (tid < NCLS) bcs[tid] = bc[tid];
    __syncthreads();
    int lane = tid & 15;
    int node = blockIdx.x * 16 + (tid >> 4);
    float acc = agg[node * HID + lane] + b2[lane];
    float l0 = bcs[lane];
    float l1 = bcs[lane + 16];
    float l2 = (lane < 8) ? bcs[lane + 32] : 0.0f;
    int base = tid & 48;
    for (int k = 0; k < HID; k++) {
        float v = __shfl(acc, base + k, 64);
        l0 += v * wcs[k * NCLS + lane];
        l1 += v * wcs[k * NCLS + lane + 16];
        if (lane < 8) l2 += v * wcs[k * NCLS + lane + 32];
    }
    float m = fmaxf(l0, l1);
    if (lane < 8) m = fmaxf(m, l2);
    for (int o = 1; o < 16; o <<= 1) m = fmaxf(m, __shfl_xor(m, o, 64));
    float s = expf(l0 - m) + expf(l1 - m) + ((lane < 8) ? expf(l2 - m) : 0.0f);
    for (int o = 1; o < 16; o <<= 1) s += __shfl_xor(s, o, 64);
    float ls = logf(s) + m;
    out[node * NCLS + lane] = l0 - ls;
    out[node * NCLS + lane + 16] = l1 - ls;
    if (lane < 8) out[node * NCLS + lane + 32] = l2 - ls;
}

extern "C" void kernel_launch(void* const* d_in, const int* in_sizes, int n_in,
                              void* d_out, int out_size, void* d_ws, size_t ws_size,
                              hipStream_t stream) {
    const float* z     = (const float*)d_in[0];
    const int*   eidx  = (const int*)d_in[1];
    const float* eattr = (const float*)d_in[2];
    const float* W1    = (const float*)d_in[3];
    const float* b1    = (const float*)d_in[4];
    const float* W2    = (const float*)d_in[5];
    const float* b2    = (const float*)d_in[6];
    const float* Wc    = (const float*)d_in[7];
    const float* bc    = (const float*)d_in[8];
    float* out = (float*)d_out;

    char* ws = (char*)d_ws;
    const int* rowp = eidx;
    const int* colp = eidx + N_EDGES;

    int nblk = (N_NODES + 255) / 256;               // 391
    int eblk = N_EDGES / 256;                       // 25000
    int sblk = (N_NODES + 1023) / 1024;             // 98
    int gblk = (N_NODES + 63) / 64;                 // 1563
    int ablk = N_NODES / 16;                        // 6250
    int fblk = (N_NODES * HID) / 256;               // 6250
    int exblk = (N_EDGES * HID) / 256;              // 400000

    if (ws_size >= (size_t)WS_T1_NEED) {
        // ---------- tier-1: atomic-free CSR build ----------
        int*   cbase = (int*)(ws + OFF_CB);
        int*   tot   = (int*)(ws + OFF_TOT);
        float* dinv  = (float*)(ws + OFF_DINV);
        int*   offs  = (int*)(ws + OFF_OFFS);
        int*   hist  = (int*)(ws + OFF_HIST);
        int2*  ebuf1 = (int2*)(ws + OFF_EBUF1);
        int2*  edat  = (int2*)(ws + OFF_EDATA);
        float* h1    = (float*)(ws + OFF_H1);
        float* hb    = (float*)(ws + OFF_HB);

        k_hist<<<B_PART, 256, 0, stream>>>(colp, hist);
        k_colscan<<<K_BKT, 256, 0, stream>>>(hist, tot);
        k_basescan<<<1, 256, 0, stream>>>(tot, cbase);
        k_partition<<<B_PART, 256, 0, stream>>>(rowp, colp, eattr, hist, cbase, ebuf1);
        k_bucketsort<<<K_BKT, 256, 0, stream>>>(ebuf1, cbase, edat, offs, dinv);
        k_gemm1<<<gblk, 256, 0, stream>>>(z, W1, h1, dinv);      // h1 overlays dead ebuf1
        k_agg1<<<ablk, 256, 0, stream>>>(h1, dinv, offs, edat, b1, W2, hb);
        k_agg2<<<ablk, 256, 0, stream>>>(hb, dinv, offs, edat, b2, Wc, bc, out);
    } else if (ws_size >= (size_t)WS_T2_NEED) {
        // ---------- tier-2: atomic-CSR path (R5) ----------
        float* dinv = (float*)(ws + T2_DINV);
        int*   cnt  = (int*)(ws + T2_CNT);
        int*   offs = (int*)(ws + T2_OFFS);
        int2*  edat = (int2*)(ws + T2_EDATA);
        float* h1   = (float*)(ws + T2_H1);
        float* hb   = (float*)(ws + T2_HB);
        int*   bsum = (int*)(ws + T2_BSUM);

        k_init<<<nblk, 256, 0, stream>>>(cnt);
        k_count<<<eblk, 256, 0, stream>>>(colp, cnt);
        k_scan1<<<sblk, 1024, 0, stream>>>(cnt, offs, bsum);
        k_scan2<<<1, 128, 0, stream>>>(bsum);
        k_scan3<<<sblk, 1024, 0, stream>>>(offs, cnt, bsum);
        k_scatter<<<eblk, 256, 0, stream>>>(rowp, colp, eattr, cnt, edat);
        k_deg_dinv<<<ablk, 256, 0, stream>>>(offs, edat, dinv);
        k_gemm1<<<gblk, 256, 0, stream>>>(z, W1, h1, dinv);
        k_agg1<<<ablk, 256, 0, stream>>>(h1, dinv, offs, edat, b1, W2, hb);
        k_agg2<<<ablk, 256, 0, stream>>>(hb, dinv, offs, edat, b2, Wc, bc, out);
    } else {
        // ---------- tier-3: edge-atomic fallback ----------
        float* deg = (float*)(ws + OFF3_DEG);
        float* h1  = (float*)(ws + OFF3_H1);
        float* hb  = (float*)(ws + OFF3_HB);

        k_init_deg<<<nblk, 256, 0, stream>>>(deg);
        k_deg_only<<<eblk, 256, 0, stream>>>(colp, eattr, deg);
        k_dinv<<<nblk, 256, 0, stream>>>(deg);
        k_gemm1<<<gblk, 256, 0, stream>>>(z, W1, hb, nullptr);
        k_self<<<fblk, 256, 0, stream>>>(deg, hb, h1);
        k_edge_atomic<<<exblk, 256, 0, stream>>>(rowp, colp, eattr, deg, hb, h1);
        k_bias_relu_gemm2<<<ablk, 256, 0, stream>>>(h1, b1, W2, hb);
        k_self<<<fblk, 256, 0, stream>>>(deg, hb, h1);
        k_edge_atomic<<<exblk, 256, 0, stream>>>(rowp, colp, eattr, deg, hb, h1);
        k_final<<<ablk, 256, 0, stream>>>(h1, b2, Wc, bc, out);
    }
}

// Round 8
// 495.043 us; speedup vs baseline: 2.8423x; 1.0720x over previous
//
#include <hip/hip_runtime.h>
#include <hip/hip_bf16.h>

// GCN inference: conv1(128->16)+ReLU -> conv2(16->16) -> linear(16->40) -> log_softmax
// R7 post-mortem: 8x unroll fixed agg latency (736->531us). k_partition now top
// (107us) at OccupancyPercent=15.8% -- launch-width-limited (400 blocks x 4 waves
// = 6.25 waves/CU). R8: 1024-thread blocks for hist/partition/bucketsort (4x the
// waves, identical algorithm). Everything else unchanged.

#define N_NODES 100000
#define N_EDGES 6400000
#define IN_DIM  128
#define HID     16
#define NCLS    40

#define K_BKT   196          // buckets = col>>9, 512 nodes each (last: 160)
#define B_PART  400          // histogram/partition blocks, 16000 edges each
#define CHUNK   16000

// ---- tier-1 workspace layout (bytes) ----
#define OFF_CB    0          // int[197] bucket bases (exclusive scan of totals)
#define OFF_TOT   1024       // int[196] bucket totals
#define OFF_DINV  2048       // float[N]
#define OFF_OFFS  402176     // int[N+1]
#define OFF_HIST  802304     // int[400*196]
#define OFF_EBUF1 1116160    // int2[E] bucket-major edges (dead after bucketsort)
#define OFF_EDATA 52316160   // int2[E] final CSR (row, w)
#define WS_T1_NEED 103600000
// h1/hb overlay the dead ebuf1 region:
#define OFF_H1    OFF_EBUF1              // float[N*16]
#define OFF_HB    (OFF_EBUF1 + 6400000)  // float[N*16]

// ---- tier-2 workspace layout (R5 atomic-CSR path) ----
#define T2_DINV  0
#define T2_CNT   400128
#define T2_OFFS  800256
#define T2_EDATA 1200384
#define T2_H1    52400384
#define T2_HB    58800384
#define T2_BSUM  65200384
#define WS_T2_NEED 65210000

// ---- tier-3 fallback layout ----
#define OFF3_DEG 0
#define OFF3_H1  400128
#define OFF3_HB  6800384

// =================== tier-1: deterministic CSR build ===================

__global__ __launch_bounds__(1024) void k_hist(const int* col, int* hist) {
    __shared__ int h[K_BKT];
    int t = threadIdx.x;
    if (t < K_BKT) h[t] = 0;
    __syncthreads();
    int b = blockIdx.x;
    for (int e = b * CHUNK + t; e < (b + 1) * CHUNK; e += 1024)
        atomicAdd(&h[col[e] >> 9], 1);                // LDS atomic: no HBM traffic
    __syncthreads();
    if (t < K_BKT) hist[b * K_BKT + t] = h[t];
}

// one block per bucket k: exclusive-scan hist[.][k] over the 400 blocks
__global__ __launch_bounds__(256) void k_colscan(int* hist, int* tot) {
    __shared__ int s[512];
    int t = threadIdx.x;
    int k = blockIdx.x;
    int v0 = (t < B_PART) ? hist[t * K_BKT + k] : 0;
    int v1 = (t + 256 < B_PART) ? hist[(t + 256) * K_BKT + k] : 0;
    s[t] = v0; s[t + 256] = v1;
    __syncthreads();
    for (int o = 1; o < 512; o <<= 1) {
        int a0 = (t >= o) ? s[t - o] : 0;
        int a1 = (t + 256 >= o) ? s[t + 256 - o] : 0;
        __syncthreads();
        s[t] += a0; s[t + 256] += a1;
        __syncthreads();
    }
    if (t < B_PART) hist[t * K_BKT + k] = s[t] - v0;  // exclusive
    if (t + 256 < B_PART) hist[(t + 256) * K_BKT + k] = s[t + 256] - v1;
    if (t == 0) tot[k] = s[B_PART - 1];               // inclusive total
}

__global__ __launch_bounds__(256) void k_basescan(const int* tot, int* cbase) {
    __shared__ int s[256];
    int t = threadIdx.x;
    int v = (t < K_BKT) ? tot[t] : 0;
    s[t] = v;
    __syncthreads();
    for (int o = 1; o < 256; o <<= 1) {
        int a = (t >= o) ? s[t - o] : 0;
        __syncthreads();
        s[t] += a;
        __syncthreads();
    }
    if (t < K_BKT) cbase[t] = s[t] - v;               // exclusive
    if (t == 0) cbase[K_BKT] = N_EDGES;
}

// partition edges into bucket-major ebuf1; packed = row | (col_local<<17)
__global__ __launch_bounds__(1024) void k_partition(const int* row, const int* col,
                                                    const float* w, const int* hist,
                                                    const int* cbase, int2* ebuf1) {
    __shared__ int cur[K_BKT];
    int t = threadIdx.x;
    int b = blockIdx.x;
    if (t < K_BKT) cur[t] = cbase[t] + hist[b * K_BKT + t];
    __syncthreads();
    for (int e = b * CHUNK + t; e < (b + 1) * CHUNK; e += 1024) {
        int c = col[e];
        int k = c >> 9;
        int p = atomicAdd(&cur[k], 1);                // LDS atomic
        ebuf1[p] = make_int2(row[e] | ((c & 511) << 17), __float_as_int(w[e]));
    }
}

// per-bucket: fine counting sort (512 local nodes) -> edata CSR; also offs + dinv.
__global__ __launch_bounds__(1024) void k_bucketsort(const int2* ebuf1, const int* cbase,
                                                     int2* edata, int* offs, float* dinv) {
    __shared__ int   cnt[512];
    __shared__ float degw[512];
    __shared__ int   sc[512];
    __shared__ int   cur[512];
    int t = threadIdx.x;
    int k = blockIdx.x;
    if (t < 512) { cnt[t] = 0; degw[t] = 0.0f; }
    __syncthreads();
    int e0 = cbase[k], e1 = cbase[k + 1];
    for (int e = e0 + t; e < e1; e += 1024) {         // pass A: local histogram + deg
        int2 v = ebuf1[e];
        int cl = v.x >> 17;
        atomicAdd(&cnt[cl], 1);
        atomicAdd(&degw[cl], __int_as_float(v.y));
    }
    __syncthreads();
    int c0 = (t < 512) ? cnt[t] : 0;
    if (t < 512) sc[t] = c0;
    __syncthreads();
    for (int o = 1; o < 512; o <<= 1) {               // inclusive scan of 512
        int a = (t < 512 && t >= o) ? sc[t - o] : 0;
        __syncthreads();
        if (t < 512) sc[t] += a;
        __syncthreads();
    }
    // exclusive offsets; emit offs + dinv for this bucket's nodes
    if (t < 512) {
        int ex = sc[t] - c0;
        cur[t] = e0 + ex;
        int node = k * 512 + t;
        if (node < N_NODES) {
            offs[node] = e0 + ex;
            dinv[node] = rsqrtf(1.0f + degw[t]);
        }
    }
    if (k == 0 && t == 0) offs[N_NODES] = N_EDGES;
    __syncthreads();
    for (int e = e0 + t; e < e1; e += 1024) {         // pass B: scatter (L2-local window)
        int2 v = ebuf1[e];
        int cl = v.x >> 17;
        int p = atomicAdd(&cur[cl], 1);               // LDS atomic
        edata[p] = make_int2(v.x & 131071, v.y);
    }
}

// =================== shared compute kernels ===================

// h1 = dinv[node] * (z @ W1); dinv=nullptr -> unscaled (tier-3)
__global__ __launch_bounds__(256) void k_gemm1(const float* z, const float* W1, float* h1,
                                               const float* dinv) {
    __shared__ float w1s[IN_DIM * HID];
    __shared__ float zs[64 * 132];
    int tid = threadIdx.x;
    for (int i = tid; i < IN_DIM * HID / 4; i += 256)
        ((float4*)w1s)[i] = ((const float4*)W1)[i];
    int nodeBase = blockIdx.x * 64;
    for (int i = tid; i < 64 * 32; i += 256) {
        int nl = i >> 5, kq = i & 31;
        int node = nodeBase + nl;
        float4 v = (node < N_NODES) ? ((const float4*)z)[node * 32 + kq]
                                    : make_float4(0.f, 0.f, 0.f, 0.f);
        *(float4*)&zs[nl * 132 + kq * 4] = v;
    }
    __syncthreads();
    int nl = tid >> 2;
    int jb = (tid & 3) * 4;
    int node = nodeBase + nl;
    float4 acc = make_float4(0.f, 0.f, 0.f, 0.f);
    for (int k = 0; k < IN_DIM; k++) {
        float s = zs[nl * 132 + k];
        float4 wv = *(const float4*)&w1s[k * HID + jb];
        acc.x += s * wv.x; acc.y += s * wv.y; acc.z += s * wv.z; acc.w += s * wv.w;
    }
    if (node < N_NODES) {
        float dv = dinv ? dinv[node] : 1.0f;
        acc.x *= dv; acc.y *= dv; acc.z *= dv; acc.w *= dv;
        ((float4*)h1)[node * 4 + (tid & 3)] = acc;
    }
}

// 8x-unrolled CSR edge aggregation: 8 independent edata loads + 8 independent
// gathers in flight per 16-lane group.
__device__ __forceinline__ float edge_agg(const float* __restrict__ h,
                                          const int2* __restrict__ edata,
                                          int e0, int e1, int lane, float acc) {
    int e = e0;
    for (; e + 8 <= e1; e += 8) {
        int2 d0 = edata[e];
        int2 d1 = edata[e + 1];
        int2 d2 = edata[e + 2];
        int2 d3 = edata[e + 3];
        int2 d4 = edata[e + 4];
        int2 d5 = edata[e + 5];
        int2 d6 = edata[e + 6];
        int2 d7 = edata[e + 7];
        float g0 = h[d0.x * HID + lane];
        float g1 = h[d1.x * HID + lane];
        float g2 = h[d2.x * HID + lane];
        float g3 = h[d3.x * HID + lane];
        float g4 = h[d4.x * HID + lane];
        float g5 = h[d5.x * HID + lane];
        float g6 = h[d6.x * HID + lane];
        float g7 = h[d7.x * HID + lane];
        acc += __int_as_float(d0.y) * g0;
        acc += __int_as_float(d1.y) * g1;
        acc += __int_as_float(d2.y) * g2;
        acc += __int_as_float(d3.y) * g3;
        acc += __int_as_float(d4.y) * g4;
        acc += __int_as_float(d5.y) * g5;
        acc += __int_as_float(d6.y) * g6;
        acc += __int_as_float(d7.y) * g7;
    }
    for (; e < e1; e++) {
        int2 ed = edata[e];
        acc += __int_as_float(ed.y) * h[ed.x * HID + lane];
    }
    return acc;
}

// conv1 aggregate (+b1, ReLU), fused h2 = x1 @ W2; hb = dinv * h2
__global__ __launch_bounds__(256) void k_agg1(const float* h1, const float* dinv,
                                              const int* offs, const int2* edata,
                                              const float* b1, const float* W2, float* hb) {
    __shared__ float w2s[HID * HID];
    int tid = threadIdx.x;
    if (tid < HID * HID) w2s[tid] = W2[tid];
    __syncthreads();
    int lane = tid & 15;
    int node = blockIdx.x * 16 + (tid >> 4);
    int e0 = offs[node], e1 = offs[node + 1];
    float acc = edge_agg(h1, edata, e0, e1, lane, h1[node * HID + lane]);
    float d = dinv[node];
    acc = d * acc + b1[lane];
    acc = fmaxf(acc, 0.0f);
    int base = tid & 48;
    float h2 = 0.0f;
    for (int k = 0; k < HID; k++) {
        float v = __shfl(acc, base + k, 64);
        h2 += v * w2s[k * HID + lane];
    }
    hb[node * HID + lane] = d * h2;
}

// conv2 aggregate (+b2), classifier (16->40) + log_softmax
__global__ __launch_bounds__(256) void k_agg2(const float* hb, const float* dinv,
                                              const int* offs, const int2* edata,
                                              const float* b2, const float* Wc,
                                              const float* bc, float* out) {
    __shared__ float wcs[HID * NCLS];
    __shared__ float bcs[NCLS];
    int tid = threadIdx.x;
    for (int i = tid; i < HID * NCLS; i += 256) wcs[i] = Wc[i];
    if (tid < NCLS) bcs[tid] = bc[tid];
    __syncthreads();
    int lane = tid & 15;
    int node = blockIdx.x * 16 + (tid >> 4);
    int e0 = offs[node], e1 = offs[node + 1];
    float acc = edge_agg(hb, edata, e0, e1, lane, hb[node * HID + lane]);
    acc = dinv[node] * acc + b2[lane];
    float l0 = bcs[lane];
    float l1 = bcs[lane + 16];
    float l2 = (lane < 8) ? bcs[lane + 32] : 0.0f;
    int base = tid & 48;
    for (int k = 0; k < HID; k++) {
        float v = __shfl(acc, base + k, 64);
        l0 += v * wcs[k * NCLS + lane];
        l1 += v * wcs[k * NCLS + lane + 16];
        if (lane < 8) l2 += v * wcs[k * NCLS + lane + 32];
    }
    float m = fmaxf(l0, l1);
    if (lane < 8) m = fmaxf(m, l2);
    for (int o = 1; o < 16; o <<= 1) m = fmaxf(m, __shfl_xor(m, o, 64));
    float s = expf(l0 - m) + expf(l1 - m) + ((lane < 8) ? expf(l2 - m) : 0.0f);
    for (int o = 1; o < 16; o <<= 1) s += __shfl_xor(s, o, 64);
    float ls = logf(s) + m;
    out[node * NCLS + lane] = l0 - ls;
    out[node * NCLS + lane + 16] = l1 - ls;
    if (lane < 8) out[node * NCLS + lane + 32] = l2 - ls;
}

// =================== tier-2: R5 atomic-CSR build ===================

__global__ __launch_bounds__(256) void k_init(int* cnt) {
    int i = blockIdx.x * 256 + threadIdx.x;
    if (i < N_NODES) cnt[i] = 0;
}

__global__ __launch_bounds__(256) void k_count(const int* col, int* cnt) {
    int e = blockIdx.x * 256 + threadIdx.x;
    atomicAdd(&cnt[col[e]], 1);
}

__global__ __launch_bounds__(1024) void k_scan1(const int* cnt, int* offs, int* bsum) {
    __shared__ int s[1024];
    int tid = threadIdx.x;
    int gid = blockIdx.x * 1024 + tid;
    int v = (gid < N_NODES) ? cnt[gid] : 0;
    s[tid] = v;
    __syncthreads();
    for (int o = 1; o < 1024; o <<= 1) {
        int t = (tid >= o) ? s[tid - o] : 0;
        __syncthreads();
        s[tid] += t;
        __syncthreads();
    }
    if (gid < N_NODES) offs[gid] = s[tid] - v;
    if (tid == 1023) bsum[blockIdx.x] = s[1023];
}

__global__ __launch_bounds__(128) void k_scan2(int* bsum) {
    __shared__ int s[128];
    int tid = threadIdx.x;
    int v = (tid < 98) ? bsum[tid] : 0;
    s[tid] = v;
    __syncthreads();
    for (int o = 1; o < 128; o <<= 1) {
        int t = (tid >= o) ? s[tid - o] : 0;
        __syncthreads();
        s[tid] += t;
        __syncthreads();
    }
    if (tid < 98) bsum[tid] = s[tid] - v;
}

__global__ __launch_bounds__(1024) void k_scan3(int* offs, int* cur, const int* bsum) {
    int tid = threadIdx.x;
    int gid = blockIdx.x * 1024 + tid;
    if (gid < N_NODES) {
        int o = offs[gid] + bsum[blockIdx.x];
        offs[gid] = o;
        cur[gid] = o;
    }
    if (gid == 0) offs[N_NODES] = N_EDGES;
}

__global__ __launch_bounds__(256) void k_scatter(const int* row, const int* col,
                                                 const float* w, int* cur, int2* edata) {
    int e = blockIdx.x * 256 + threadIdx.x;
    int r = row[e];
    int c = col[e];
    int p = atomicAdd(&cur[c], 1);
    edata[p] = make_int2(r, __float_as_int(w[e]));
}

__global__ __launch_bounds__(256) void k_deg_dinv(const int* offs, const int2* edata,
                                                  float* dinv) {
    int tid = threadIdx.x;
    int lane = tid & 15;
    int node = blockIdx.x * 16 + (tid >> 4);
    int e0 = offs[node], e1 = offs[node + 1];
    float s = 0.0f;
    for (int e = e0 + lane; e < e1; e += 16)
        s += __int_as_float(edata[e].y);
    for (int o = 1; o < 16; o <<= 1) s += __shfl_xor(s, o, 64);
    if (lane == 0) dinv[node] = 1.0f / sqrtf(1.0f + s);
}

// =================== tier-3: edge-atomic fallback ===================

__global__ __launch_bounds__(256) void k_init_deg(float* deg) {
    int i = blockIdx.x * 256 + threadIdx.x;
    if (i < N_NODES) deg[i] = 1.0f;
}

__global__ __launch_bounds__(256) void k_deg_only(const int* col, const float* w, float* deg) {
    int e = blockIdx.x * 256 + threadIdx.x;
    atomicAdd(&deg[col[e]], w[e]);
}

__global__ __launch_bounds__(256) void k_dinv(float* deg) {
    int i = blockIdx.x * 256 + threadIdx.x;
    if (i < N_NODES) {
        float d = deg[i];
        deg[i] = (d > 0.0f) ? 1.0f / sqrtf(d) : 0.0f;
    }
}

__global__ __launch_bounds__(256) void k_self(const float* dinv, const float* h, float* agg) {
    int i = blockIdx.x * 256 + threadIdx.x;
    float d = dinv[i >> 4];
    agg[i] = d * d * h[i];
}

__global__ __launch_bounds__(256) void k_edge_atomic(const int* row, const int* col,
                                                     const float* w, const float* dinv,
                                                     const float* h, float* agg) {
    int gid = blockIdx.x * 256 + threadIdx.x;
    int e = gid >> 4, lane = gid & 15;
    int r = row[e], c = col[e];
    float nrm = dinv[r] * w[e] * dinv[c];
    atomicAdd(&agg[c * HID + lane], nrm * h[r * HID + lane]);
}

__global__ __launch_bounds__(256) void k_bias_relu_gemm2(const float* agg, const float* b1,
                                                         const float* W2, float* out2) {
    __shared__ float w2s[HID * HID];
    int tid = threadIdx.x;
    if (tid < HID * HID) w2s[tid] = W2[tid];
    __syncthreads();
    int lane = tid & 15;
    int node = blockIdx.x * 16 + (tid >> 4);
    float acc = fmaxf(agg[node * HID + lane] + b1[lane], 0.0f);
    int base = tid & 48;
    float h2 = 0.0f;
    for (int k = 0; k < HID; k++) {
        float v = __shfl(acc, base + k, 64);
        h2 += v * w2s[k * HID + lane];
    }
    out2[node * HID + lane] = h2;
}

__global__ __launch_bounds__(256) void k_final(const float* agg, const float* b2,
                                               const float* Wc, const float* bc, float* out) {
    __shared__ float wcs[HID * NCLS];
    __shared__ float bcs[NCLS];
    int tid = threadIdx.x;
    for (int i = tid; i < HID * NCLS; i += 256) wcs[i] = Wc[i];
    if (tid < NCLS) bcs[tid] = bc[tid];
    __syncthreads();
    int lane = tid & 15;
    int node = blockIdx.x * 16 + (tid >> 4);
    float acc = agg[node * HID + lane] + b2[lane];
    float l0 = bcs[lane];
    float l1 = bcs[lane + 16];
    float l2 = (lane < 8) ? bcs[lane + 32] : 0.0f;
    int base = tid & 48;
    for (int k = 0; k < HID; k++) {
        float v = __shfl(acc, base + k, 64);
        l0 += v * wcs[k * NCLS + lane];
        l1 += v * wcs[k * NCLS + lane + 16];
        if (lane < 8) l2 += v * wcs[k * NCLS + lane + 32];
    }
    float m = fmaxf(l0, l1);
    if (lane < 8) m = fmaxf(m, l2);
    for (int o = 1; o < 16; o <<= 1) m = fmaxf(m, __shfl_xor(m, o, 64));
    float s = expf(l0 - m) + expf(l1 - m) + ((lane < 8) ? expf(l2 - m) : 0.0f);
    for (int o = 1; o < 16; o <<= 1) s += __shfl_xor(s, o, 64);
    float ls = logf(s) + m;
    out[node * NCLS + lane] = l0 - ls;
    out[node * NCLS + lane + 16] = l1 - ls;
    if (lane < 8) out[node * NCLS + lane + 32] = l2 - ls;
}

extern "C" void kernel_launch(void* const* d_in, const int* in_sizes, int n_in,
                              void* d_out, int out_size, void* d_ws, size_t ws_size,
                              hipStream_t stream) {
    const float* z     = (const float*)d_in[0];
    const int*   eidx  = (const int*)d_in[1];
    const float* eattr = (const float*)d_in[2];
    const float* W1    = (const float*)d_in[3];
    const float* b1    = (const float*)d_in[4];
    const float* W2    = (const float*)d_in[5];
    const float* b2    = (const float*)d_in[6];
    const float* Wc    = (const float*)d_in[7];
    const float* bc    = (const float*)d_in[8];
    float* out = (float*)d_out;

    char* ws = (char*)d_ws;
    const int* rowp = eidx;
    const int* colp = eidx + N_EDGES;

    int nblk = (N_NODES + 255) / 256;               // 391
    int eblk = N_EDGES / 256;                       // 25000
    int sblk = (N_NODES + 1023) / 1024;             // 98
    int gblk = (N_NODES + 63) / 64;                 // 1563
    int ablk = N_NODES / 16;                        // 6250
    int fblk = (N_NODES * HID) / 256;               // 6250
    int exblk = (N_EDGES * HID) / 256;              // 400000

    if (ws_size >= (size_t)WS_T1_NEED) {
        // ---------- tier-1: atomic-free CSR build ----------
        int*   cbase = (int*)(ws + OFF_CB);
        int*   tot   = (int*)(ws + OFF_TOT);
        float* dinv  = (float*)(ws + OFF_DINV);
        int*   offs  = (int*)(ws + OFF_OFFS);
        int*   hist  = (int*)(ws + OFF_HIST);
        int2*  ebuf1 = (int2*)(ws + OFF_EBUF1);
        int2*  edat  = (int2*)(ws + OFF_EDATA);
        float* h1    = (float*)(ws + OFF_H1);
        float* hb    = (float*)(ws + OFF_HB);

        k_hist<<<B_PART, 1024, 0, stream>>>(colp, hist);
        k_colscan<<<K_BKT, 256, 0, stream>>>(hist, tot);
        k_basescan<<<1, 256, 0, stream>>>(tot, cbase);
        k_partition<<<B_PART, 1024, 0, stream>>>(rowp, colp, eattr, hist, cbase, ebuf1);
        k_bucketsort<<<K_BKT, 1024, 0, stream>>>(ebuf1, cbase, edat, offs, dinv);
        k_gemm1<<<gblk, 256, 0, stream>>>(z, W1, h1, dinv);      // h1 overlays dead ebuf1
        k_agg1<<<ablk, 256, 0, stream>>>(h1, dinv, offs, edat, b1, W2, hb);
        k_agg2<<<ablk, 256, 0, stream>>>(hb, dinv, offs, edat, b2, Wc, bc, out);
    } else if (ws_size >= (size_t)WS_T2_NEED) {
        // ---------- tier-2: atomic-CSR path (R5) ----------
        float* dinv = (float*)(ws + T2_DINV);
        int*   cnt  = (int*)(ws + T2_CNT);
        int*   offs = (int*)(ws + T2_OFFS);
        int2*  edat = (int2*)(ws + T2_EDATA);
        float* h1   = (float*)(ws + T2_H1);
        float* hb   = (float*)(ws + T2_HB);
        int*   bsum = (int*)(ws + T2_BSUM);

        k_init<<<nblk, 256, 0, stream>>>(cnt);
        k_count<<<eblk, 256, 0, stream>>>(colp, cnt);
        k_scan1<<<sblk, 1024, 0, stream>>>(cnt, offs, bsum);
        k_scan2<<<1, 128, 0, stream>>>(bsum);
        k_scan3<<<sblk, 1024, 0, stream>>>(offs, cnt, bsum);
        k_scatter<<<eblk, 256, 0, stream>>>(rowp, colp, eattr, cnt, edat);
        k_deg_dinv<<<ablk, 256, 0, stream>>>(offs, edat, dinv);
        k_gemm1<<<gblk, 256, 0, stream>>>(z, W1, h1, dinv);
        k_agg1<<<ablk, 256, 0, stream>>>(h1, dinv, offs, edat, b1, W2, hb);
        k_agg2<<<ablk, 256, 0, stream>>>(hb, dinv, offs, edat, b2, Wc, bc, out);
    } else {
        // ---------- tier-3: edge-atomic fallback ----------
        float* deg = (float*)(ws + OFF3_DEG);
        float* h1  = (float*)(ws + OFF3_H1);
        float* hb  = (float*)(ws + OFF3_HB);

        k_init_deg<<<nblk, 256, 0, stream>>>(deg);
        k_deg_only<<<eblk, 256, 0, stream>>>(colp, eattr, deg);
        k_dinv<<<nblk, 256, 0, stream>>>(deg);
        k_gemm1<<<gblk, 256, 0, stream>>>(z, W1, hb, nullptr);
        k_self<<<fblk, 256, 0, stream>>>(deg, hb, h1);
        k_edge_atomic<<<exblk, 256, 0, stream>>>(rowp, colp, eattr, deg, hb, h1);
        k_bias_relu_gemm2<<<ablk, 256, 0, stream>>>(h1, b1, W2, hb);
        k_self<<<fblk, 256, 0, stream>>>(deg, hb, h1);
        k_edge_atomic<<<exblk, 256, 0, stream>>>(rowp, colp, eattr, deg, hb, h1);
        k_final<<<ablk, 256, 0, stream>>>(h1, b2, Wc, bc, out);
    }
}